// Round 16
// baseline (16018.309 us; speedup 1.0000x reference)
//
#include <hip/hip_runtime.h>
#include <math.h>

#define B 4
#define SEQ 33
#define MAXLEN 32
#define D 640
#define NH 8
#define DH 80
#define NL 6
#define FF 2560
#define V 30000
#define INITLEN 8
#define NBLK 1024
#define NT 256
#define EOS_TOK 2
#define NPOS_P 9
#define NR_P 36
#define LM_NB 938   // ceil(30000/32)

// decode stage block ranges
#define QKV_N 240
#define AW_B 240
#define AW_E 304
#define F1_B 304
#define F1_E 624
#define F2_B 624
#define F2_E 784

// striped stage flags: 32 slots x 64B per flag (proven layout)
#define NFLAGS 1024
#define NSLOT 32
#define SLOT_U 16   // uints per slot (64 bytes)

#define VER(t,l) ((size_t)((t) * NL + (l)))

typedef float f4 __attribute__((ext_vector_type(4)));

struct Par {
  const int* iw;
  const float* emb;
  const float *Wq, *bq, *Wk, *bk, *Wv, *bv, *Wo, *bo;
  const float *ln1s, *ln1b, *W1, *b1, *W2, *b2, *ln2s, *ln2b, *lmW, *lmb;
  int* out;
};

// ---------------- persistent device scratch ----------------------------------
__device__ __align__(256) float g_Kc[(size_t)NL * B * NH * SEQ * DH];
__device__ __align__(256) float g_Vc[(size_t)NL * B * NH * SEQ * DH];
// versioned decode buffers: write-once per (t,l) -> plain cached reads are safe
__device__ __align__(256) float g_xv[(size_t)SEQ * NL * 2560];     // layer input [b][col]
__device__ __align__(256) float g_h1v[(size_t)SEQ * NL * 2560];    // LN1 out [b][col]
__device__ __align__(256) float g_qv[(size_t)SEQ * NL * 2560];     // q [col][b]
__device__ __align__(256) float g_opartv[(size_t)SEQ * NL * 20480];// [h][b][col]
__device__ __align__(256) float g_f1v[(size_t)SEQ * NL * 10240];   // relu'd [b][f]
__device__ __align__(256) float g_f2v[(size_t)SEQ * NL * 5120];    // [hf][b][col]
__device__ __align__(256) float g_xlm[(size_t)SEQ * 2560];         // LM input (prefill step only)
__device__ __align__(256) int   g_tokv[SEQ * 64];
__device__ __align__(256) int   g_stopv[SEQ * 64];  // doubles as CTL->all flag: 1|stop<<1
// prefill buffers (36 rows)
__device__ float g_xp[NR_P * D];
__device__ float g_h1p[NR_P * D];
__device__ float g_qkvpP[(size_t)8 * 1920 * NR_P];
__device__ float g_qP[(size_t)NH * NR_P * DH];
__device__ float g_opartP[(size_t)NH * D * NR_P];
__device__ float g_f1pP[(size_t)8 * FF * NR_P];
__device__ float g_f2pP[(size_t)32 * D * NR_P];
// control
__device__ unsigned long long g_keys[(size_t)NBLK * B];
__device__ int g_tokens[B * SEQ];
__device__ unsigned g_flags[(size_t)NFLAGS * NSLOT * SLOT_U];
__device__ unsigned g_arrive = 0;
__device__ unsigned g_gen = 0;

#define KCIDX(l,b,h,pos,j) (((((size_t)(l)*B+(b))*NH+(h))*SEQ+(pos))*DH+(j))

// ---------------- coherent access (sc1 = device scope) -----------------------
__device__ __forceinline__ float ldc(const float* p) {
  return __hip_atomic_load(p, __ATOMIC_RELAXED, __HIP_MEMORY_SCOPE_AGENT);
}
__device__ __forceinline__ void stc(float* p, float v) {
  __hip_atomic_store(p, v, __ATOMIC_RELAXED, __HIP_MEMORY_SCOPE_AGENT);
}
__device__ __forceinline__ int ldci(const int* p) {
  return __hip_atomic_load(p, __ATOMIC_RELAXED, __HIP_MEMORY_SCOPE_AGENT);
}
__device__ __forceinline__ void stci(int* p, int v) {
  __hip_atomic_store(p, v, __ATOMIC_RELAXED, __HIP_MEMORY_SCOPE_AGENT);
}
__device__ __forceinline__ void stcu64(unsigned long long* p, unsigned long long v) {
  __hip_atomic_store(p, v, __ATOMIC_RELAXED, __HIP_MEMORY_SCOPE_AGENT);
}
// 16B device-scope store (write-through to MALL)
__device__ __forceinline__ void st4c(float* p, f4 v) {
  asm volatile("global_store_dwordx4 %0, %1, off sc1" :: "v"(p), "v"(v) : "memory");
}
// 16B device-scope load: ISSUE ONLY. Must call wait_vm() before using results.
__device__ __forceinline__ void ld4c_issue(f4& dst, const float* p) {
  asm volatile("global_load_dwordx4 %0, %1, off sc1" : "=v"(dst) : "v"(p) : "memory");
}
__device__ __forceinline__ void wait_vm() {
  asm volatile("s_waitcnt vmcnt(0)" ::: "memory");
  __builtin_amdgcn_sched_barrier(0);
}
__device__ __forceinline__ unsigned long long mk64(float lo, float hi) {
  return ((unsigned long long)__float_as_uint(hi) << 32) | (unsigned long long)__float_as_uint(lo);
}
// keep a value alive so prefetch loads are not DCE'd (guide rule #17)
__device__ __forceinline__ void keep(float x) { asm volatile("" :: "v"(x)); }

// ---------------- init-time full grid barrier --------------------------------
__device__ __forceinline__ void gsync_full() {
  __syncthreads();
  if (threadIdx.x == 0) {
    __threadfence();
    unsigned g = __hip_atomic_load(&g_gen, __ATOMIC_SEQ_CST, __HIP_MEMORY_SCOPE_AGENT);
    unsigned old = __hip_atomic_fetch_add(&g_arrive, 1u, __ATOMIC_SEQ_CST, __HIP_MEMORY_SCOPE_AGENT);
    if (old == NBLK - 1u) {
      __hip_atomic_store(&g_arrive, 0u, __ATOMIC_SEQ_CST, __HIP_MEMORY_SCOPE_AGENT);
      __hip_atomic_fetch_add(&g_gen, 1u, __ATOMIC_SEQ_CST, __HIP_MEMORY_SCOPE_AGENT);
    } else {
      while (__hip_atomic_load(&g_gen, __ATOMIC_RELAXED, __HIP_MEMORY_SCOPE_AGENT) == g)
        __builtin_amdgcn_s_sleep(2);
    }
    __threadfence();
  }
  __syncthreads();
}

// ---------------- fence-free striped stage sync ------------------------------
__device__ __forceinline__ void stage_done(int idx) {
  asm volatile("s_waitcnt vmcnt(0)" ::: "memory");  // every wave drains its stores
  __syncthreads();
  if (threadIdx.x == 0) {
    __hip_atomic_fetch_add(
        &g_flags[((size_t)idx * NSLOT + (blockIdx.x & (NSLOT - 1))) * SLOT_U],
        1u, __ATOMIC_RELAXED, __HIP_MEMORY_SCOPE_AGENT);
  }
}

__device__ __forceinline__ void stage_wait(int idx, unsigned cnt) {
  if (threadIdx.x < 64) {
    const unsigned* base = &g_flags[(size_t)idx * NSLOT * SLOT_U];
    int spins = 0;
    for (;;) {
      unsigned v = 0u;
      if (threadIdx.x < NSLOT)
        v = __hip_atomic_load(base + (size_t)threadIdx.x * SLOT_U,
                              __ATOMIC_RELAXED, __HIP_MEMORY_SCOPE_AGENT);
      #pragma unroll
      for (int o = 16; o > 0; o >>= 1) v += __shfl_down(v, o, 64);
      v = __shfl(v, 0, 64);
      if (v >= cnt) break;
      // spin-first: the ~1us poll RTT is natural pacing; sleep only later
      if (spins < 8)        { /* pure spin */ }
      else if (spins < 64)  __builtin_amdgcn_s_sleep(1);
      else if (spins < 192) __builtin_amdgcn_s_sleep(8);
      else                  __builtin_amdgcn_s_sleep(32);
      ++spins;
    }
  }
  __syncthreads();
  asm volatile("" ::: "memory");
}

// ---------------- LN helpers -------------------------------------------------
__device__ __forceinline__ float bred_sum(float v, float* s_red) {
  #pragma unroll
  for (int o = 32; o > 0; o >>= 1) v += __shfl_down(v, o, 64);
  __syncthreads();
  if ((threadIdx.x & 63) == 0) s_red[threadIdx.x >> 6] = v;
  __syncthreads();
  return s_red[0] + s_red[1] + s_red[2] + s_red[3];
}

__device__ void ln_inplace(float* row, const float* gam, const float* bet, float* s_red) {
  float ps = 0.f;
  for (int d = threadIdx.x; d < D; d += NT) ps += row[d];
  const float m = bred_sum(ps, s_red) * (1.0f / 640.0f);
  float pv = 0.f;
  for (int d = threadIdx.x; d < D; d += NT) { float t = row[d] - m; pv += t * t; }
  const float var = bred_sum(pv, s_red) * (1.0f / 640.0f);
  const float rstd = 1.0f / sqrtf(var + 1e-6f);
  for (int d = threadIdx.x; d < D; d += NT)
    row[d] = (row[d] - m) * rstd * gam[d] + bet[d];
  __syncthreads();
}

// wave-local LN over s_x[w][640], wave w = row w. No barriers inside.
__device__ __forceinline__ void ln_wave(float* s_x, const float* gam, const float* bet) {
  const int tid = threadIdx.x, w = tid >> 6, lane = tid & 63;
  float ps = 0.f;
  for (int i = lane; i < D; i += 64) ps += s_x[w * 640 + i];
  #pragma unroll
  for (int o = 32; o > 0; o >>= 1) ps += __shfl_xor(ps, o, 64);
  const float mean = ps * (1.0f / 640.0f);
  float pv = 0.f;
  for (int i = lane; i < D; i += 64) { float d = s_x[w * 640 + i] - mean; pv += d * d; }
  #pragma unroll
  for (int o = 32; o > 0; o >>= 1) pv += __shfl_xor(pv, o, 64);
  const float rstd = 1.0f / sqrtf(pv * (1.0f / 640.0f) + 1e-6f);
  for (int i = lane; i < D; i += 64)
    s_x[w * 640 + i] = (s_x[w * 640 + i] - mean) * rstd * gam[i] + bet[i];
}

// s_x[w][640] = LN2_{lsrc}( h1v + f2v(2 halves) + b2 ). Wave w = batch row w.
// Deterministic (wave-local shuffles) -> bit-identical across all blocks.
__device__ __forceinline__ void build_x2w(const Par& p, int t, int lsrc, float* s_x) {
  const int tid = threadIdx.x, w = tid >> 6, lane = tid & 63;
  const size_t ver = VER(t, lsrc);
  const float* h1 = g_h1v + ver * 2560 + w * 640;
  const float* fa = g_f2v + ver * 5120 + w * 640;
  const float* fb = g_f2v + ver * 5120 + 2560 + w * 640;
  const float* b2 = p.b2 + (size_t)lsrc * D;
  for (int c4 = lane; c4 < 160; c4 += 64) {
    f4 a = *(const f4*)&h1[c4 * 4];
    f4 b = *(const f4*)&fa[c4 * 4];
    f4 c = *(const f4*)&fb[c4 * 4];
    const float* bb = b2 + c4 * 4;
    f4 s = { a.x + b.x + c.x + bb[0], a.y + b.y + c.y + bb[1],
             a.z + b.z + c.z + bb[2], a.w + b.w + c.w + bb[3] };
    *(f4*)&s_x[w * 640 + c4 * 4] = s;
  }
  ln_wave(s_x, p.ln2s + (size_t)lsrc * D, p.ln2b + (size_t)lsrc * D);
}

// =================== LAYER-SCOPED WEIGHT PREFETCH ============================
// Issue EXACTLY the loads the upcoming GEMM will perform (plain cached),
// BEFORE the final stage_wait, with a ONE-STAGE residency window so the lines
// survive in L2 until use. NO pf for LM (9.6MB/XCD, 2.4x L2 -> R12).

__device__ void pf_QKV(const Par& p, int l) {
  const int tid = threadIdx.x;
  const int cg = (blockIdx.x & 7) * 30 + (blockIdx.x >> 3);
  const int m = cg / 80, colm0 = (cg % 80) * 8;
  const int ds = tid >> 3, c = tid & 7;
  const float* Wb = (m == 0 ? p.Wq : m == 1 ? p.Wk : p.Wv)
                    + (size_t)l * D * D + colm0 + c;
  float s = 0.f;
  #pragma unroll
  for (int j = 0; j < 20; ++j) s += Wb[(size_t)(ds + j * 32) * D];
  keep(s);
}

__device__ void pf_AW(const Par& p, int l) {
  const int idx = blockIdx.x - AW_B, h = idx >> 3, c = idx & 7, tid = threadIdx.x;
  if (tid < 240) {
    const int j = tid % 80, sub = tid / 80;
    const int col = c * 80 + j;
    const int d0 = sub * 27, d1 = (sub == 2) ? 80 : d0 + 27;
    const float* Wo = p.Wo + (size_t)l * D * D + col;
    float s = 0.f;
    for (int dd = d0; dd < d1; ++dd) s += Wo[(size_t)(h * 80 + dd) * D];
    keep(s);
  }
}

__device__ void pf_F1(const Par& p, int l) {
  const int tid = threadIdx.x;
  const int raw = blockIdx.x - F1_B;
  const int cg = (raw & 7) * 40 + (raw >> 3);
  const int col0 = cg * 8;
  const int ds = tid >> 3, c = tid & 7;
  const float* Wb = p.W1 + (size_t)l * D * FF + col0 + c;
  float s = 0.f;
  #pragma unroll
  for (int j = 0; j < 20; ++j) s += Wb[(size_t)(ds + j * 32) * FF];
  keep(s);
}

__device__ void pf_F2(const Par& p, int l) {
  const int idx = blockIdx.x - F2_B, tid = threadIdx.x;
  const int hf = idx / 80, craw = idx % 80;
  const int cg = (craw & 7) * 10 + (craw >> 3);
  const int col0 = cg * 8;
  const int ds = tid >> 3, c = tid & 7;
  const float* Wb = p.W2 + (size_t)l * FF * D + (size_t)hf * 1280 * D + col0 + c;
  float s = 0.f;
  #pragma unroll
  for (int kb = 0; kb < 40; ++kb) s += Wb[(size_t)(ds + kb * 32) * D];
  keep(s);
}

// =================== DECODE STAGES ===========================================

// QKV (fused LN2 of previous layer): blocks [0,240): 8 cols of 1920,
// full depth 640. XCD-grouped slice swizzle (240 = 8*30).
__device__ void st_QKV(const Par& p, int l, int t, float* s_x, float* s_t, float* s_r) {
  const int tid = threadIdx.x;
  const int cg = (blockIdx.x & 7) * 30 + (blockIdx.x >> 3);   // bijective
  const int m = cg / 80, colm0 = (cg % 80) * 8;
  const int w = tid >> 6, lane = tid & 63;
  if (l == 0) {
    const int tok = g_tokv[t * 64 + w];          // versioned, plain
    for (int c4 = lane; c4 < 160; c4 += 64)
      *(f4*)&s_x[w * 640 + c4 * 4] = *(const f4*)&p.emb[(size_t)tok * D + c4 * 4];
  } else {
    build_x2w(p, t, l - 1, s_x);
  }
  __syncthreads();
  if (cg == 0) {  // publish x for F1's residual (blockIdx 0 -> cg 0)
    const size_t xo = VER(t, l) * 2560;
    for (int i = tid; i < 640; i += NT)
      st4c(&g_xv[xo + (size_t)i * 4], *(f4*)&s_x[i * 4]);
  }
  // ---- GEMM: 8 cols, full depth 640; thread = (ds in [0,32), c in [0,8)).
  const int ds = tid >> 3, c = tid & 7;
  const float* Wb = (m == 0 ? p.Wq : m == 1 ? p.Wk : p.Wv)
                    + (size_t)l * D * D + colm0 + c;
  float a0 = 0, a1 = 0, a2 = 0, a3 = 0;
  {
    float wv[20];
    #pragma unroll
    for (int j = 0; j < 20; ++j) wv[j] = Wb[(size_t)(ds + j * 32) * D];
    #pragma unroll
    for (int j = 0; j < 20; ++j) {
      const int dd = ds + j * 32;
      a0 = fmaf(s_x[dd],        wv[j], a0);
      a1 = fmaf(s_x[640 + dd],  wv[j], a1);
      a2 = fmaf(s_x[1280 + dd], wv[j], a2);
      a3 = fmaf(s_x[1920 + dd], wv[j], a3);
    }
  }
  { f4 av = { a0, a1, a2, a3 }; *(f4*)&s_t[c * 132 + ds * 4] = av; }
  __syncthreads();
  if (tid < 32) {
    const int c2 = tid >> 2, b = tid & 3;
    float v = 0.f;
    #pragma unroll
    for (int d2 = 0; d2 < 32; ++d2) v += s_t[c2 * 132 + d2 * 4 + b];
    v += (m == 0 ? p.bq : m == 1 ? p.bk : p.bv)[(size_t)l * D + colm0 + c2];
    s_r[c2 * 4 + b] = v;
  }
  __syncthreads();
  if (m == 0) {
    if (tid < 8) {
      f4 v = { s_r[tid * 4], s_r[tid * 4 + 1], s_r[tid * 4 + 2], s_r[tid * 4 + 3] };
      st4c(&g_qv[VER(t, l) * 2560 + (size_t)(colm0 + tid) * 4], v);
    }
  } else {
    const int h = colm0 / 80, j0 = colm0 % 80;
    if (tid < 8) {
      const int b = tid >> 1, cq4 = (tid & 1) * 4;
      f4 v = { s_r[(cq4+0)*4+b], s_r[(cq4+1)*4+b], s_r[(cq4+2)*4+b], s_r[(cq4+3)*4+b] };
      float* cache = (m == 1) ? g_Kc : g_Vc;
      st4c(&cache[KCIDX(l, b, h, t, j0 + cq4)], v);
    }
  }
}

// AW: blocks [240,304): h=(idx)>>3, c=idx&7. q + all KV rows plain cached.
__device__ void st_AW(const Par& p, int l, int t,
                      float* s_q, float* s_sc, float* s_o, float* s_wo) {
  const int idx = blockIdx.x - AW_B, h = idx >> 3, c = idx & 7, tid = threadIdx.x;
  const size_t qo = VER(t, l) * 2560;
  if (tid < 80) {
    f4 q = *(const f4*)&g_qv[qo + (size_t)(h * 80 + tid) * 4];
    s_q[tid] = q.x; s_q[80 + tid] = q.y; s_q[160 + tid] = q.z; s_q[240 + tid] = q.w;
  }
  __syncthreads();
  const int nk = t + 1;
  for (int task = tid; task < 4 * nk; task += NT) {
    const int b = task / nk, kp = task % nk;
    const float* qq = s_q + b * 80;
    const f4* kk = (const f4*)&g_Kc[KCIDX(l, b, h, kp, 0)];
    float sd = 0.f;
    #pragma unroll
    for (int j4 = 0; j4 < 20; ++j4) {
      f4 k4 = kk[j4];
      sd += qq[j4*4+0]*k4.x + qq[j4*4+1]*k4.y + qq[j4*4+2]*k4.z + qq[j4*4+3]*k4.w;
    }
    s_sc[b * 33 + kp] = sd / 8.94427190999915878564f;
  }
  __syncthreads();
  if (tid < 4) {
    const int b = tid;
    float m = -1e30f;
    for (int k = 0; k < nk; ++k) m = fmaxf(m, s_sc[b * 33 + k]);
    float sum = 0.f;
    for (int k = 0; k < nk; ++k) { float e = expf(s_sc[b * 33 + k] - m); s_sc[b * 33 + k] = e; sum += e; }
    s_sc[132 + b] = 1.0f / sum;
  }
  __syncthreads();
  if (tid < 80) {
    const int b = tid / 20, j4 = tid % 20;
    f4 acc = { 0.f, 0.f, 0.f, 0.f };
    for (int kp = 0; kp < nk; ++kp) {
      f4 v = *(const f4*)&g_Vc[KCIDX(l, b, h, kp, j4 * 4)];
      const float wgt = s_sc[b * 33 + kp];
      acc.x += wgt * v.x; acc.y += wgt * v.y; acc.z += wgt * v.z; acc.w += wgt * v.w;
    }
    const float r = s_sc[132 + b];
    f4 o = { acc.x * r, acc.y * r, acc.z * r, acc.w * r };
    *(f4*)&s_o[b * 80 + j4 * 4] = o;
  }
  __syncthreads();
  // Wo partial: cols [c*80,+80), rows h*80+[0,80) split in 3 subs
  if (tid < 240) {
    const int j = tid % 80, sub = tid / 80;
    const int col = c * 80 + j;
    const int d0 = sub * 27, d1 = (sub == 2) ? 80 : d0 + 27;
    const float* Wo = p.Wo + (size_t)l * D * D + col;
    float a0 = 0, a1 = 0, a2 = 0, a3 = 0;
    #pragma unroll 9
    for (int dd = d0; dd < d1; ++dd) {
      const float w = Wo[(size_t)(h * 80 + dd) * D];
      a0 += s_o[0*80+dd] * w; a1 += s_o[80+dd] * w;
      a2 += s_o[160+dd] * w; a3 += s_o[240+dd] * w;
    }
    float* tp = s_wo + (j * 3 + sub) * 4;
    tp[0] = a0; tp[1] = a1; tp[2] = a2; tp[3] = a3;
  }
  __syncthreads();
  if (tid < 80) {
    const int b = tid / 20, cq = tid % 20;
    f4 v;
    #pragma unroll
    for (int i = 0; i < 4; ++i) {
      const int j = cq * 4 + i;
      v[i] = s_wo[(j*3+0)*4+b] + s_wo[(j*3+1)*4+b] + s_wo[(j*3+2)*4+b];
    }
    st4c(&g_opartv[VER(t, l) * 20480 + (size_t)(h * 4 + b) * 640 + c * 80 + cq * 4], v);
  }
}

// F1 (fused residual + LN1): blocks [304,624): 8 cols of FF, full depth.
// Each block builds h1 = LN1(xv + bo + sum_h opartv) wave-locally, then GEMM.
// raw==0 publishes h1v. XCD-grouped swizzle (320 = 8*40).
__device__ void st_F1(const Par& p, int l, int t, float* s_x, float* s_t, float* s_r) {
  const int tid = threadIdx.x;
  const int raw = blockIdx.x - F1_B;
  const int cg = (raw & 7) * 40 + (raw >> 3);
  const int col0 = cg * 8;
  const size_t ver = VER(t, l);
  const int w = tid >> 6, lane = tid & 63;
  // ---- residual + LN1, wave w = batch row w
  {
    const float* xv = g_xv + ver * 2560 + w * 640;
    const float* bo = p.bo + (size_t)l * D;
    for (int c4 = lane; c4 < 160; c4 += 64) {
      f4 a = *(const f4*)&xv[c4 * 4];
      const float* bb = bo + c4 * 4;
      a.x += bb[0]; a.y += bb[1]; a.z += bb[2]; a.w += bb[3];
      #pragma unroll
      for (int h = 0; h < 8; ++h) {
        f4 ov = *(const f4*)&g_opartv[ver * 20480 + (size_t)(h * 4 + w) * 640 + c4 * 4];
        a.x += ov.x; a.y += ov.y; a.z += ov.z; a.w += ov.w;
      }
      *(f4*)&s_x[w * 640 + c4 * 4] = a;
    }
    ln_wave(s_x, p.ln1s + (size_t)l * D, p.ln1b + (size_t)l * D);
  }
  __syncthreads();
  if (raw == 0) {  // publish h1 for next-layer QKV / LM
    for (int i = tid; i < 640; i += NT)
      st4c(&g_h1v[ver * 2560 + (size_t)i * 4], *(f4*)&s_x[i * 4]);
  }
  // ---- GEMM: 8 cols, depth 640; thread = (ds in [0,32), c in [0,8)).
  const int ds = tid >> 3, c = tid & 7;
  const float* Wb = p.W1 + (size_t)l * D * FF + col0 + c;
  float a0 = 0, a1 = 0, a2 = 0, a3 = 0;
  {
    float wv[20];
    #pragma unroll
    for (int j = 0; j < 20; ++j) wv[j] = Wb[(size_t)(ds + j * 32) * FF];
    #pragma unroll
    for (int j = 0; j < 20; ++j) {
      const int dd = ds + j * 32;
      a0 = fmaf(s_x[dd],        wv[j], a0);
      a1 = fmaf(s_x[640 + dd],  wv[j], a1);
      a2 = fmaf(s_x[1280 + dd], wv[j], a2);
      a3 = fmaf(s_x[1920 + dd], wv[j], a3);
    }
  }
  { f4 av = { a0, a1, a2, a3 }; *(f4*)&s_t[c * 132 + ds * 4] = av; }
  __syncthreads();
  if (tid < 32) {
    const int c2 = tid >> 2, b = tid & 3;
    float v = 0.f;
    #pragma unroll
    for (int d2 = 0; d2 < 32; ++d2) v += s_t[c2 * 132 + d2 * 4 + b];
    v += p.b1[(size_t)l * FF + col0 + c2];
    s_r[c2 * 4 + b] = fmaxf(v, 0.f);
  }
  __syncthreads();
  if (tid < 8) {
    const int b = tid >> 1, cq4 = (tid & 1) * 4;
    f4 v = { s_r[(cq4+0)*4+b], s_r[(cq4+1)*4+b], s_r[(cq4+2)*4+b], s_r[(cq4+3)*4+b] };
    st4c(&g_f1v[ver * 10240 + (size_t)b * 2560 + col0 + cq4], v);
  }
}

// F2: blocks [624,784): hf=idx/80 (depth half), 8 cols, depth 1280.
// XCD-grouped swizzle within each hf (80 = 8*10).
__device__ void st_F2(const Par& p, int l, int t, float* s_f, float* s_t, float* s_r) {
  const int idx = blockIdx.x - F2_B, tid = threadIdx.x;
  const int hf = idx / 80, craw = idx % 80;
  const int cg = (craw & 7) * 10 + (craw >> 3);
  const int col0 = cg * 8;
  const size_t ver = VER(t, l);
  #pragma unroll
  for (int i = 0; i < 5; ++i) {
    const int ii = tid + i * NT;              // 0..1279
    const int b = ii / 320, fo = ii % 320;
    *(f4*)&s_f[b * 1280 + fo * 4] =
        *(const f4*)&g_f1v[ver * 10240 + (size_t)b * 2560 + hf * 1280 + fo * 4];
  }
  __syncthreads();
  // ---- GEMM: 8 cols, depth 1280; thread = (ds in [0,32), c in [0,8)), 2x20.
  const int ds = tid >> 3, c = tid & 7;
  const float* Wb = p.W2 + (size_t)l * FF * D + (size_t)hf * 1280 * D + col0 + c;
  float a0 = 0, a1 = 0, a2 = 0, a3 = 0;
  #pragma unroll
  for (int kb = 0; kb < 40; kb += 20) {
    float wv[20];
    #pragma unroll
    for (int j = 0; j < 20; ++j) wv[j] = Wb[(size_t)(ds + (kb + j) * 32) * D];
    #pragma unroll
    for (int j = 0; j < 20; ++j) {
      const int dl = ds + (kb + j) * 32;
      a0 = fmaf(s_f[dl],        wv[j], a0);
      a1 = fmaf(s_f[1280 + dl], wv[j], a1);
      a2 = fmaf(s_f[2560 + dl], wv[j], a2);
      a3 = fmaf(s_f[3840 + dl], wv[j], a3);
    }
  }
  { f4 av = { a0, a1, a2, a3 }; *(f4*)&s_t[c * 132 + ds * 4] = av; }
  __syncthreads();
  if (tid < 32) {
    const int c2 = tid >> 2, b = tid & 3;
    float v = 0.f;
    #pragma unroll
    for (int d2 = 0; d2 < 32; ++d2) v += s_t[c2 * 132 + d2 * 4 + b];
    s_r[c2 * 4 + b] = v;
  }
  __syncthreads();
  if (tid < 8) {
    const int b = tid >> 1, cq4 = (tid & 1) * 4;
    f4 v = { s_r[(cq4+0)*4+b], s_r[(cq4+1)*4+b], s_r[(cq4+2)*4+b], s_r[(cq4+3)*4+b] };
    st4c(&g_f2v[ver * 5120 + (size_t)(hf * 4 + b) * 640 + col0 + cq4], v);
  }
}

// LM: blocks [0,938): 32 cols each, depth split 8x80, 4x20 batched weights.
// src==1 (decode steps): build x = LN2(h1v+f2v) wave-locally (fused RL).
// src==0 (first step): read prefill-produced g_xlm.
// Bijective XCD chunk swizzle (938 = 8*117 + 2).
__device__ void st_LM(const Par& p, int t, int src, float* s_xf, float* s_part,
                      unsigned long long* s_key) {
  const int bid = blockIdx.x, tid = threadIdx.x;
  const int xcd = bid & 7, jj = bid >> 3;
  const int chunk = (xcd < 2 ? xcd * 118 : 236 + (xcd - 2) * 117) + jj;
  if (src == 0) {
    #pragma unroll
    for (int i = 0; i < 3; ++i) {
      const int idx = tid + i * NT;
      if (idx < 640) *(f4*)&s_xf[idx * 4] = *(const f4*)&g_xlm[(size_t)t * 2560 + (size_t)idx * 4];
    }
  } else {
    build_x2w(p, t, NL - 1, s_xf);
  }
  __syncthreads();
  const int sg = tid >> 5, cj = tid & 31;
  const int col = chunk * 32 + cj;
  float a0 = 0, a1 = 0, a2 = 0, a3 = 0;
  if (col < V) {
    const float* W = p.lmW + (size_t)sg * 80 * V + col;
    #pragma unroll
    for (int kb = 0; kb < 80; kb += 20) {
      float w[20];
      #pragma unroll
      for (int j = 0; j < 20; ++j) w[j] = W[(size_t)(kb + j) * V];
      #pragma unroll
      for (int j = 0; j < 20; ++j) {
        const int d = sg * 80 + kb + j;
        a0 = fmaf(s_xf[d],        w[j], a0);
        a1 = fmaf(s_xf[640 + d],  w[j], a1);
        a2 = fmaf(s_xf[1280 + d], w[j], a2);
        a3 = fmaf(s_xf[1920 + d], w[j], a3);
      }
    }
  }
  float* tp = s_part + (sg * 32 + cj) * 4;
  tp[0] = a0; tp[1] = a1; tp[2] = a2; tp[3] = a3;
  __syncthreads();
  if (tid < 128) {
    const int cj2 = tid >> 2, b = tid & 3, col2 = chunk * 32 + cj2;
    unsigned long long key = 0ull;
    if (col2 < V) {
      float a = p.lmb[col2];
      #pragma unroll
      for (int sg2 = 0; sg2 < 8; ++sg2) a += s_part[(sg2 * 32 + cj2) * 4 + b];
      unsigned u = __float_as_uint(a);
      u = (u & 0x80000000u) ? ~u : (u | 0x80000000u);
      key = ((unsigned long long)u << 32) | (unsigned)(V - col2);
    }
    s_key[cj2 * 4 + b] = key;
  }
  __syncthreads();
  if (tid < 4) {
    unsigned long long k0 = 0ull;
    for (int cj2 = 0; cj2 < 32; ++cj2) {
      const unsigned long long k = s_key[cj2 * 4 + tid];
      if (k > k0) k0 = k;
    }
    stcu64(&g_keys[(size_t)bid * B + tid], k0);
  }
}

// CTL: block 1023. Batched 16B sc1 loads, all 4 batch rows in one pass.
// Final verdict is signaled via g_stopv[t*64] = 1 | stop<<1 (always nonzero),
// AFTER a vmcnt drain so token stores are visible first. No separate flag hop.
__device__ void st_CTL(int t, unsigned long long* s_k64, int* s_ctl) {
  const int tid = threadIdx.x;
  const int i0 = tid, i1 = tid + NT, i2 = tid + 2 * NT, i3 = tid + 3 * NT;
  f4 z = { 0.f, 0.f, 0.f, 0.f };
  f4 ka0, kb0, ka1, kb1, ka2, kb2, ka3 = z, kb3 = z;
  ld4c_issue(ka0, (const float*)&g_keys[(size_t)i0 * 4]);
  ld4c_issue(kb0, (const float*)&g_keys[(size_t)i0 * 4 + 2]);
  ld4c_issue(ka1, (const float*)&g_keys[(size_t)i1 * 4]);
  ld4c_issue(kb1, (const float*)&g_keys[(size_t)i1 * 4 + 2]);
  ld4c_issue(ka2, (const float*)&g_keys[(size_t)i2 * 4]);
  ld4c_issue(kb2, (const float*)&g_keys[(size_t)i2 * 4 + 2]);
  if (i3 < LM_NB) {
    ld4c_issue(ka3, (const float*)&g_keys[(size_t)i3 * 4]);
    ld4c_issue(kb3, (const float*)&g_keys[(size_t)i3 * 4 + 2]);
  }
  wait_vm();
  unsigned long long m0 = mk64(ka0.x, ka0.y), m1 = mk64(ka0.z, ka0.w);
  unsigned long long m2 = mk64(kb0.x, kb0.y), m3 = mk64(kb0.z, kb0.w);
  { unsigned long long s;
    s = mk64(ka1.x,ka1.y); if (s>m0) m0=s;  s = mk64(ka1.z,ka1.w); if (s>m1) m1=s;
    s = mk64(kb1.x,kb1.y); if (s>m2) m2=s;  s = mk64(kb1.z,kb1.w); if (s>m3) m3=s;
    s = mk64(ka2.x,ka2.y); if (s>m0) m0=s;  s = mk64(ka2.z,ka2.w); if (s>m1) m1=s;
    s = mk64(kb2.x,kb2.y); if (s>m2) m2=s;  s = mk64(kb2.z,kb2.w); if (s>m3) m3=s;
    s = mk64(ka3.x,ka3.y); if (s>m0) m0=s;  s = mk64(ka3.z,ka3.w); if (s>m1) m1=s;
    s = mk64(kb3.x,kb3.y); if (s>m2) m2=s;  s = mk64(kb3.z,kb3.w); if (s>m3) m3=s;
  }
  #pragma unroll
  for (int o = 32; o > 0; o >>= 1) {
    unsigned long long s;
    s = __shfl_down(m0, o, 64); if (s > m0) m0 = s;
    s = __shfl_down(m1, o, 64); if (s > m1) m1 = s;
    s = __shfl_down(m2, o, 64); if (s > m2) m2 = s;
    s = __shfl_down(m3, o, 64); if (s > m3) m3 = s;
  }
  if ((tid & 63) == 0) {
    const int w = tid >> 6;
    s_k64[w * 4 + 0] = m0; s_k64[w * 4 + 1] = m1;
    s_k64[w * 4 + 2] = m2; s_k64[w * 4 + 3] = m3;
  }
  __syncthreads();
  if (tid == 0) {
    #pragma unroll
    for (int b = 0; b < B; ++b) {
      unsigned long long k0 = s_k64[b];
      #pragma unroll
      for (int w = 1; w < 4; ++w) if (s_k64[w * 4 + b] > k0) k0 = s_k64[w * 4 + b];
      const int tok = V - (int)(unsigned)(k0 & 0xFFFFFFFFull);
      stci(&g_tokens[b * SEQ + t + 1], tok);
      stci(&g_tokv[(t + 1) * 64 + b], tok);
      s_ctl[b] = tok;
    }
    int stop = (t == MAXLEN - 1) ? 1 : 0;
    if (s_ctl[0] == EOS_TOK && s_ctl[1] == EOS_TOK &&
        s_ctl[2] == EOS_TOK && s_ctl[3] == EOS_TOK) stop = 1;
    // drain token stores, then publish the verdict (nonzero = ready)
    asm volatile("s_waitcnt vmcnt(0)" ::: "memory");
    stci(&g_stopv[t * 64], 1 | (stop << 1));
  }
}

// =================== PREFILL STAGES (36 rows, sc1 scalar; runs once) =========

__device__ void st_Qp(const Par& p, int l, float* s_a) {
  const int idx = blockIdx.x, tid = threadIdx.x;
  const int h = idx / 24, rem = idx % 24, s = rem / 3, rg = rem % 3;
  const int r0 = rg * 12, d0 = s * 80;
  for (int i = tid; i < 960; i += NT) {
    const int ri = i / 80, dd = i % 80;
    s_a[i] = ldc(&g_xp[(r0 + ri) * D + d0 + dd]);
  }
  __syncthreads();
  if (tid < 240) {
    const int m = tid / 80, j = tid % 80, col = h * 80 + j;
    const float* W = (m == 0 ? p.Wq : m == 1 ? p.Wk : p.Wv) + (size_t)l * D * D + col;
    float acc[12];
    #pragma unroll
    for (int ri = 0; ri < 12; ++ri) acc[ri] = 0.f;
    for (int dd = 0; dd < 80; ++dd) {
      const float w = W[(size_t)(d0 + dd) * D];
      #pragma unroll
      for (int ri = 0; ri < 12; ++ri) acc[ri] += s_a[ri * 80 + dd] * w;
    }
    float* o = g_qkvpP + ((size_t)s * 1920 + m * 640 + col) * NR_P + r0;
    #pragma unroll
    for (int ri = 0; ri < 12; ++ri) stc(o + ri, acc[ri]);
  }
}

__device__ void st_AWp1(const Par& p, int l) {
  const int idx = blockIdx.x - 192, h = idx >> 2, c = idx & 3, tid = threadIdx.x;
  for (int pp = c; pp < NPOS_P; pp += 4) {
    for (int task = tid; task < 960; task += NT) {
      const int m = task / 320, rem = task % 320, j = rem >> 2, b = rem & 3;
      const int r = pp * 4 + b;
      const int col = m * 640 + h * 80 + j;
      const float* q = g_qkvpP + (size_t)col * NR_P + r;
      float a = 0.f;
      #pragma unroll
      for (int s = 0; s < 8; ++s) a += ldc(q + (size_t)s * 1920 * NR_P);
      a += (m == 0 ? p.bq : m == 1 ? p.bk : p.bv)[(size_t)l * D + h * 80 + j];
      if (m == 0)      stc(&g_qP[((size_t)h * NR_P + r) * DH + j], a);
      else if (m == 1) stc(&g_Kc[KCIDX(l, b, h, pp, j)], a);
      else             stc(&g_Vc[KCIDX(l, b, h, pp, j)], a);
    }
  }
}

__device__ void st_AWp2(const Par& p, int l, float* s_a, float* s_b, float* s_c) {
  const int idx = blockIdx.x - 224, h = idx >> 2, rg = idx & 3, tid = threadIdx.x;
  const int r0 = rg * 9;
  for (int i = tid; i < 720; i += NT) {
    const int ri = i / 80, j = i % 80;
    s_a[i] = ldc(&g_qP[((size_t)h * NR_P + r0 + ri) * DH + j]);
  }
  __syncthreads();
  for (int task = tid; task < 81; task += NT) {
    const int ri = task / 9, kp = task % 9;
    const int r = r0 + ri, pos = r >> 2, b = r & 3;
    if (kp <= pos) {
      const float* kk = g_Kc + KCIDX(l, b, h, kp, 0);
      const float* qq = s_a + ri * 80;
      float sd = 0.f;
      for (int j = 0; j < 80; ++j) sd += qq[j] * ldc(kk + j);
      s_c[ri * 9 + kp] = sd / 8.94427190999915878564f;
    }
  }
  __syncthreads();
  if (tid < 9) {
    const int ri = tid, r = r0 + ri, pos = r >> 2;
    float m = -1e30f;
    for (int k = 0; k <= pos; ++k) m = fmaxf(m, s_c[ri * 9 + k]);
    float sum = 0.f;
    for (int k = 0; k <= pos; ++k) { float e = expf(s_c[ri * 9 + k] - m); s_c[ri * 9 + k] = e; sum += e; }
    s_c[81 + ri] = 1.0f / sum;
  }
  __syncthreads();
  for (int task = tid; task < 720; task += NT) {
    const int ri = task / 80, j = task % 80;
    const int r = r0 + ri, pos = r >> 2, b = r & 3;
    float acc = 0.f;
    for (int kp = 0; kp <= pos; ++kp)
      acc += s_c[ri * 9 + kp] * ldc(&g_Vc[KCIDX(l, b, h, kp, j)]);
    s_b[ri * 80 + j] = acc * s_c[81 + ri];
  }
  __syncthreads();
  if (tid < 160) {
    for (int pass = 0; pass < 4; ++pass) {
      const int col = pass * 160 + tid;
      const float* Wo = p.Wo + (size_t)l * D * D + col;
      float acc[9];
      #pragma unroll
      for (int ri = 0; ri < 9; ++ri) acc[ri] = 0.f;
      for (int dd = 0; dd < 80; ++dd) {
        const float w = Wo[(size_t)(h * 80 + dd) * D];
        #pragma unroll
        for (int ri = 0; ri < 9; ++ri) acc[ri] += s_b[ri * 80 + dd] * w;
      }
      #pragma unroll
      for (int ri = 0; ri < 9; ++ri)
        stc(&g_opartP[((size_t)h * D + col) * NR_P + r0 + ri], acc[ri]);
    }
  }
}

__device__ void st_RFp(const Par& p, int l, float* s_row, float* s_red) {
  const int r = blockIdx.x, tid = threadIdx.x;
  for (int col = tid; col < D; col += NT) {
    float a = ldc(&g_xp[r * D + col]) + p.bo[(size_t)l * D + col];
    #pragma unroll
    for (int h = 0; h < 8; ++h) a += ldc(&g_opartP[((size_t)h * D + col) * NR_P + r]);
    s_row[col] = a;
  }
  __syncthreads();
  ln_inplace(s_row, p.ln1s + (size_t)l * D, p.ln1b + (size_t)l * D, s_red);
  for (int col = tid; col < D; col += NT) stc(&g_h1p[r * D + col], s_row[col]);
}

__device__ void st_F1p(const Par& p, int l, float* s_a) {
  const int idx = blockIdx.x, tid = threadIdx.x;
  const int s = idx / 30, rem = idx % 30, cg = rem / 3, rg = rem % 3;
  const int r0 = rg * 12, d0 = s * 80;
  for (int i = tid; i < 960; i += NT) {
    const int ri = i / 80, dd = i % 80;
    s_a[i] = ldc(&g_h1p[(r0 + ri) * D + d0 + dd]);
  }
  __syncthreads();
  const int col = cg * 256 + tid;
  const float* W = p.W1 + (size_t)l * D * FF + col;
  float acc[12];
  #pragma unroll
  for (int ri = 0; ri < 12; ++ri) acc[ri] = 0.f;
  for (int dd = 0; dd < 80; ++dd) {
    const float w = W[(size_t)(d0 + dd) * FF];
    #pragma unroll
    for (int ri = 0; ri < 12; ++ri) acc[ri] += s_a[ri * 80 + dd] * w;
  }
  float* o = g_f1pP + ((size_t)s * FF + col) * NR_P + r0;
  #pragma unroll
  for (int ri = 0; ri < 12; ++ri) stc(o + ri, acc[ri]);
}

__device__ void st_F2p(const Par& p, int l, float* s_c) {
  const int idx = blockIdx.x - 240, c = idx / 3, rg = idx % 3, tid = threadIdx.x;
  const int r0 = rg * 12;
  for (int task = tid; task < 960; task += NT) {
    const int ri = task / 80, fj = task % 80;
    const int fcol = c * 80 + fj;
    const float* pp = g_f1pP + (size_t)fcol * NR_P + r0 + ri;
    float a = 0.f;
    #pragma unroll
    for (int s = 0; s < 8; ++s) a += ldc(pp + (size_t)s * FF * NR_P);
    a += p.b1[(size_t)l * FF + fcol];
    s_c[ri * 80 + fj] = fmaxf(a, 0.f);
  }
  __syncthreads();
  for (int pass = 0; pass < 3; ++pass) {
    const int col = pass * 256 + tid;
    if (col < D) {
      const float* W = p.W2 + (size_t)l * FF * D + col;
      float acc[12];
      #pragma unroll
      for (int ri = 0; ri < 12; ++ri) acc[ri] = 0.f;
      for (int fj = 0; fj < 80; ++fj) {
        const float w = W[(size_t)(c * 80 + fj) * D];
        #pragma unroll
        for (int ri = 0; ri < 12; ++ri) acc[ri] += s_c[ri * 80 + fj] * w;
      }
      float* o = g_f2pP + ((size_t)c * D + col) * NR_P + r0;
      #pragma unroll
      for (int ri = 0; ri < 12; ++ri) stc(o + ri, acc[ri]);
    }
  }
}

__device__ void st_RQp(const Par& p, int l, float* s_row, float* s_red) {
  const int r = blockIdx.x, tid = threadIdx.x;
  for (int col = tid; col < D; col += NT) {
    float a = ldc(&g_h1p[r * D + col]) + p.b2[(size_t)l * D + col];
    #pragma unroll 8
    for (int c = 0; c < 32; ++c) a += ldc(&g_f2pP[((size_t)c * D + col) * NR_P + r]);
    s_row[col] = a;
  }
  __syncthreads();
  ln_inplace(s_row, p.ln2s + (size_t)l * D, p.ln2b + (size_t)l * D, s_red);
  for (int col = tid; col < D; col += NT) stc(&g_xp[r * D + col], s_row[col]);
}

__device__ void st_RLp(const Par& p, float* s_row, float* s_red) {
  const int b = blockIdx.x, r = 32 + b, tid = threadIdx.x;
  for (int col = tid; col < D; col += NT) {
    float a = ldc(&g_h1p[r * D + col]) + p.b2[(size_t)(NL - 1) * D + col];
    #pragma unroll 8
    for (int c = 0; c < 32; ++c) a += ldc(&g_f2pP[((size_t)c * D + col) * NR_P + r]);
    s_row[col] = a;
  }
  __syncthreads();
  ln_inplace(s_row, p.ln2s + (size_t)(NL - 1) * D, p.ln2b + (size_t)(NL - 1) * D, s_red);
  for (int col = tid; col < D; col += NT)
    stc(&g_xlm[(size_t)INITLEN * 2560 + (size_t)b * 640 + col], s_row[col]);
}

// =================== MAIN ====================================================
__global__ __launch_bounds__(NT, 4) void tfgen(Par p) {
  __shared__ float s_pool[6400];
  __shared__ float s_red[8];
  __shared__ unsigned long long s_key[128];
  __shared__ int s_ctl[8];

  const int bid = blockIdx.x, tid = threadIdx.x;
  int ep = 0;

  // ---- INIT: zero flags + stop words, prefill embeddings, token buffer
  {
    unsigned* f = g_flags + (size_t)bid * NSLOT * SLOT_U;
    for (int i = tid; i < NSLOT * SLOT_U; i += NT) f[i] = 0u;
  }
  if (bid < NR_P) {
    const int pos = bid >> 2, b = bid & 3;
    const int tk = (pos == 0) ? 1 : p.iw[b * INITLEN + pos - 1];
    for (int d = tid; d < D; d += NT) stc(&g_xp[bid * D + d], p.emb[(size_t)tk * D + d]);
  }
  if (bid == NBLK - 1) {
    for (int i = tid; i < B * SEQ; i += NT) {
      const int b = i / SEQ, pos = i % SEQ;
      int tk = 0;
      if (pos == 0) tk = 1;
      else if (pos <= INITLEN) tk = p.iw[b * INITLEN + pos - 1];
      stci(&g_tokens[i], tk);
    }
    for (int i = tid; i < SEQ; i += NT) stci(&g_stopv[i * 64], 0);  // stale-run reset
  }
  gsync_full();

  // ---- PREFILL (pool-mapped shared arrays)
  float* ps_x  = s_pool;          // 2560
  float* ps_a  = s_pool + 2560;   // 1024
  float* ps_b  = s_pool + 3584;   // 768
  float* ps_c  = s_pool + 4352;   // 1024
  int eRQ = -1, eF2last = -1;
  for (int l = 0; l < NL; ++l) {
    const int eQ = ep++;
    if (bid < 192) { if (l > 0) stage_wait(eRQ, 36); st_Qp(p, l, ps_a); stage_done(eQ); }
    const int eA1 = ep++;
    if (bid >= 192 && bid < 224) { stage_wait(eQ, 192); st_AWp1(p, l); stage_done(eA1); }
    const int eA2 = ep++;
    if (bid >= 224 && bid < 256) { stage_wait(eA1, 32); st_AWp2(p, l, ps_a, ps_b, ps_c); stage_done(eA2); }
    const int eRF = ep++;
    if (bid < NR_P) { stage_wait(eA2, 32); st_RFp(p, l, ps_x, s_red); stage_done(eRF); }
    const int eF1 = ep++;
    if (bid < 240) { stage_wait(eRF, 36); st_F1p(p, l, ps_a); stage_done(eF1); }
    const int eF2 = ep++;
    if (bid >= 240 && bid < 336) { stage_wait(eF1, 240); st_F2p(p, l, ps_c); stage_done(eF2); }
    eF2last = eF2;
    if (l < NL - 1) {
      eRQ = ep++;
      if (bid < NR_P) { stage_wait(eF2, 96); st_RQp(p, l, ps_x, s_red); stage_done(eRQ); }
    }
  }

  // ---- DECODE
  for (int t = INITLEN;; ++t) {
    if (t == INITLEN) {
      const int eRLp = ep++;
      if (bid < 4) { stage_wait(eF2last, 96); st_RLp(p, s_pool, s_red); stage_done(eRLp); }
      const int eLM = ep++;
      if (bid < LM_NB) { stage_wait(eRLp, 4); st_LM(p, t, 0, s_pool, s_pool + 2560, s_key); stage_done(eLM); }
      if (bid == NBLK - 1) { stage_wait(eLM, LM_NB); st_CTL(t, s_key, s_ctl); }
    } else {
      int eF1s = -1, eF2s = -1;
      for (int l = 0; l < NL; ++l) {
        const int eQKV = ep++;
        if (bid < QKV_N) {
          if (l > 0) {
            // wait on the (ordered-earlier) F1 flag first, THEN prefetch:
            // shrinks the pf residency window to the F2 stage only (<L2),
            // so prefetched weight lines survive until the GEMM (R15's 45%
            // eviction was the 3-stage window).
            stage_wait(eF1s, 320);
            pf_QKV(p, l);
            stage_wait(eF2s, 160);
          }
          st_QKV(p, l, t, s_pool, s_pool + 2560, s_pool + 3648);
          stage_done(eQKV);
        }
        const int eAW = ep++;
        if (bid >= AW_B && bid < AW_E) {
          pf_AW(p, l);
          stage_wait(eQKV, QKV_N);
          st_AW(p, l, t, s_pool, s_pool + 320, s_pool + 480, s_pool + 800);
          stage_done(eAW);
        }
        eF1s = ep++;
        if (bid >= F1_B && bid < F1_E) {
          pf_F1(p, l);
          stage_wait(eAW, 64);
          st_F1(p, l, t, s_pool, s_pool + 2560, s_pool + 3648);
          stage_done(eF1s);
        }
        eF2s = ep++;
        if (bid >= F2_B && bid < F2_E) {
          pf_F2(p, l);
          stage_wait(eF1s, 320);
          st_F2(p, l, t, s_pool, s_pool + 5120, s_pool + 6208);
          stage_done(eF2s);
        }
      }
      const int eLM = ep++;
      if (bid < LM_NB) { stage_wait(eF2s, 160); st_LM(p, t, 1, s_pool, s_pool + 2560, s_key); stage_done(eLM); }
      if (bid == NBLK - 1) { stage_wait(eLM, LM_NB); st_CTL(t, s_key, s_ctl); }
    }
    // layer-0 QKV weights for the NEXT step prefetch during the verdict wait
    if (bid < QKV_N) pf_QKV(p, 0);
    // all blocks: CTL's verdict word doubles as the flag (nonzero = ready;
    // token stores were vmcnt-drained before it was written).
    if (tid == 0) {
      int v, spins = 0;
      while ((v = ldci(&g_stopv[t * 64])) == 0) {
        if (spins < 8)        { /* pure spin: poll RTT paces us */ }
        else if (spins < 64)  __builtin_amdgcn_s_sleep(1);
        else if (spins < 192) __builtin_amdgcn_s_sleep(8);
        else                  __builtin_amdgcn_s_sleep(32);
        ++spins;
      }
      s_ctl[4] = v;
    }
    __syncthreads();
    asm volatile("" ::: "memory");
    if (s_ctl[4] >> 1) break;
  }

  if (bid == 0) {
    for (int i = tid; i < B * MAXLEN; i += NT) {
      const int b = i >> 5, j = i & 31;
      p.out[i] = ldci(&g_tokens[b * SEQ + j + 1]);
    }
  }
}

extern "C" void kernel_launch(void* const* d_in, const int* in_sizes, int n_in,
                              void* d_out, int out_size, void* d_ws, size_t ws_size,
                              hipStream_t stream)
{
  (void)in_sizes; (void)n_in; (void)out_size; (void)d_ws; (void)ws_size;
  Par p;
  p.iw   = (const int*)  d_in[0];
  p.emb  = (const float*)d_in[2];
  p.Wq   = (const float*)d_in[3];  p.bq   = (const float*)d_in[4];
  p.Wk   = (const float*)d_in[5];  p.bk   = (const float*)d_in[6];
  p.Wv   = (const float*)d_in[7];  p.bv   = (const float*)d_in[8];
  p.Wo   = (const float*)d_in[9];  p.bo   = (const float*)d_in[10];
  p.ln1s = (const float*)d_in[11]; p.ln1b = (const float*)d_in[12];
  p.W1   = (const float*)d_in[13]; p.b1   = (const float*)d_in[14];
  p.W2   = (const float*)d_in[15]; p.b2   = (const float*)d_in[16];
  p.ln2s = (const float*)d_in[17]; p.ln2b = (const float*)d_in[18];
  p.lmW  = (const float*)d_in[19]; p.lmb  = (const float*)d_in[20];
  p.out  = (int*)d_out;

  void* args[] = { (void*)&p };
  hipError_t err = hipLaunchCooperativeKernel((const void*)tfgen, dim3(NBLK), dim3(NT),
                                              args, 0, stream);
  if (err != hipSuccess) {
    // __launch_bounds__(256,4) guarantees 4 blocks/CU co-residency on 256 CUs.
    hipLaunchKernelGGL(tfgen, dim3(NBLK), dim3(NT), 0, stream, p);
  }
}

// Round 17
// 15917.845 us; speedup vs baseline: 1.0063x; 1.0063x over previous
//
#include <hip/hip_runtime.h>
#include <math.h>

#define B 4
#define SEQ 33
#define MAXLEN 32
#define D 640
#define NH 8
#define DH 80
#define NL 6
#define FF 2560
#define V 30000
#define INITLEN 8
#define NBLK 1024
#define NT 256
#define EOS_TOK 2
#define NPOS_P 9
#define NR_P 36
#define LM_NB 938   // ceil(30000/32)

// decode stage block ranges
#define QKV_N 240
#define AW_B 240
#define AW_E 304
#define F1_B 304
#define F1_E 624
#define F2_B 624
#define F2_E 784

// striped stage flags: 32 slots x 64B per flag (proven layout)
#define NFLAGS 1024
#define NSLOT 32
#define SLOT_U 16   // uints per slot (64 bytes)

#define VER(t,l) ((size_t)((t) * NL + (l)))

typedef float f4 __attribute__((ext_vector_type(4)));

struct Par {
  const int* iw;
  const float* emb;
  const float *Wq, *bq, *Wk, *bk, *Wv, *bv, *Wo, *bo;
  const float *ln1s, *ln1b, *W1, *b1, *W2, *b2, *ln2s, *ln2b, *lmW, *lmb;
  int* out;
};

// ---------------- persistent device scratch ----------------------------------
__device__ __align__(256) float g_Kc[(size_t)NL * B * NH * SEQ * DH];
__device__ __align__(256) float g_Vc[(size_t)NL * B * NH * SEQ * DH];
// versioned decode buffers: write-once per (t,l) -> plain cached reads are safe
__device__ __align__(256) float g_xv[(size_t)SEQ * NL * 2560];     // layer input [b][col]
__device__ __align__(256) float g_h1v[(size_t)SEQ * NL * 2560];    // LN1 out [b][col]
__device__ __align__(256) float g_qv[(size_t)SEQ * NL * 2560];     // q [col][b]
__device__ __align__(256) float g_opartv[(size_t)SEQ * NL * 20480];// [h][b][col]
__device__ __align__(256) float g_f1v[(size_t)SEQ * NL * 10240];   // relu'd [b][f]
__device__ __align__(256) float g_f2v[(size_t)SEQ * NL * 5120];    // [hf][b][col]
__device__ __align__(256) float g_xlm[(size_t)SEQ * 2560];         // LM input (prefill step only)
__device__ __align__(256) int   g_tokv[SEQ * 64];
__device__ __align__(256) int   g_stopv[SEQ * 64];  // doubles as CTL->all flag: 1|stop<<1
// prefill buffers (36 rows)
__device__ float g_xp[NR_P * D];
__device__ float g_h1p[NR_P * D];
__device__ float g_qkvpP[(size_t)8 * 1920 * NR_P];
__device__ float g_qP[(size_t)NH * NR_P * DH];
__device__ float g_opartP[(size_t)NH * D * NR_P];
__device__ float g_f1pP[(size_t)8 * FF * NR_P];
__device__ float g_f2pP[(size_t)32 * D * NR_P];
// control
__device__ unsigned long long g_keys[(size_t)NBLK * B];
__device__ int g_tokens[B * SEQ];
__device__ unsigned g_flags[(size_t)NFLAGS * NSLOT * SLOT_U];
__device__ unsigned g_arrive = 0;
__device__ unsigned g_gen = 0;

#define KCIDX(l,b,h,pos,j) (((((size_t)(l)*B+(b))*NH+(h))*SEQ+(pos))*DH+(j))

// ---------------- coherent access (sc1 = device scope) -----------------------
__device__ __forceinline__ float ldc(const float* p) {
  return __hip_atomic_load(p, __ATOMIC_RELAXED, __HIP_MEMORY_SCOPE_AGENT);
}
__device__ __forceinline__ void stc(float* p, float v) {
  __hip_atomic_store(p, v, __ATOMIC_RELAXED, __HIP_MEMORY_SCOPE_AGENT);
}
__device__ __forceinline__ int ldci(const int* p) {
  return __hip_atomic_load(p, __ATOMIC_RELAXED, __HIP_MEMORY_SCOPE_AGENT);
}
__device__ __forceinline__ void stci(int* p, int v) {
  __hip_atomic_store(p, v, __ATOMIC_RELAXED, __HIP_MEMORY_SCOPE_AGENT);
}
__device__ __forceinline__ void stcu64(unsigned long long* p, unsigned long long v) {
  __hip_atomic_store(p, v, __ATOMIC_RELAXED, __HIP_MEMORY_SCOPE_AGENT);
}
// 16B device-scope store (write-through to MALL)
__device__ __forceinline__ void st4c(float* p, f4 v) {
  asm volatile("global_store_dwordx4 %0, %1, off sc1" :: "v"(p), "v"(v) : "memory");
}
// 16B device-scope load: ISSUE ONLY. Must call wait_vm() before using results.
__device__ __forceinline__ void ld4c_issue(f4& dst, const float* p) {
  asm volatile("global_load_dwordx4 %0, %1, off sc1" : "=v"(dst) : "v"(p) : "memory");
}
__device__ __forceinline__ void wait_vm() {
  asm volatile("s_waitcnt vmcnt(0)" ::: "memory");
  __builtin_amdgcn_sched_barrier(0);
}
__device__ __forceinline__ unsigned long long mk64(float lo, float hi) {
  return ((unsigned long long)__float_as_uint(hi) << 32) | (unsigned long long)__float_as_uint(lo);
}
// keep a value alive so prefetch loads are not DCE'd (guide rule #17)
__device__ __forceinline__ void keep(float x) { asm volatile("" :: "v"(x)); }

// ---------------- init-time full grid barrier --------------------------------
__device__ __forceinline__ void gsync_full() {
  __syncthreads();
  if (threadIdx.x == 0) {
    __threadfence();
    unsigned g = __hip_atomic_load(&g_gen, __ATOMIC_SEQ_CST, __HIP_MEMORY_SCOPE_AGENT);
    unsigned old = __hip_atomic_fetch_add(&g_arrive, 1u, __ATOMIC_SEQ_CST, __HIP_MEMORY_SCOPE_AGENT);
    if (old == NBLK - 1u) {
      __hip_atomic_store(&g_arrive, 0u, __ATOMIC_SEQ_CST, __HIP_MEMORY_SCOPE_AGENT);
      __hip_atomic_fetch_add(&g_gen, 1u, __ATOMIC_SEQ_CST, __HIP_MEMORY_SCOPE_AGENT);
    } else {
      while (__hip_atomic_load(&g_gen, __ATOMIC_RELAXED, __HIP_MEMORY_SCOPE_AGENT) == g)
        __builtin_amdgcn_s_sleep(2);
    }
    __threadfence();
  }
  __syncthreads();
}

// ---------------- fence-free striped stage sync ------------------------------
__device__ __forceinline__ void stage_done(int idx) {
  asm volatile("s_waitcnt vmcnt(0)" ::: "memory");  // every wave drains its stores
  __syncthreads();
  if (threadIdx.x == 0) {
    __hip_atomic_fetch_add(
        &g_flags[((size_t)idx * NSLOT + (blockIdx.x & (NSLOT - 1))) * SLOT_U],
        1u, __ATOMIC_RELAXED, __HIP_MEMORY_SCOPE_AGENT);
  }
}

__device__ __forceinline__ void stage_wait(int idx, unsigned cnt) {
  if (threadIdx.x < 64) {
    const unsigned* base = &g_flags[(size_t)idx * NSLOT * SLOT_U];
    int spins = 0;
    for (;;) {
      unsigned v = 0u;
      if (threadIdx.x < NSLOT)
        v = __hip_atomic_load(base + (size_t)threadIdx.x * SLOT_U,
                              __ATOMIC_RELAXED, __HIP_MEMORY_SCOPE_AGENT);
      #pragma unroll
      for (int o = 16; o > 0; o >>= 1) v += __shfl_down(v, o, 64);
      v = __shfl(v, 0, 64);
      if (v >= cnt) break;
      // spin-first: the ~1us poll RTT is natural pacing; sleep only later
      if (spins < 8)        { /* pure spin */ }
      else if (spins < 64)  __builtin_amdgcn_s_sleep(1);
      else if (spins < 192) __builtin_amdgcn_s_sleep(8);
      else                  __builtin_amdgcn_s_sleep(32);
      ++spins;
    }
  }
  __syncthreads();
  asm volatile("" ::: "memory");
}

// ---------------- LN helpers -------------------------------------------------
__device__ __forceinline__ float bred_sum(float v, float* s_red) {
  #pragma unroll
  for (int o = 32; o > 0; o >>= 1) v += __shfl_down(v, o, 64);
  __syncthreads();
  if ((threadIdx.x & 63) == 0) s_red[threadIdx.x >> 6] = v;
  __syncthreads();
  return s_red[0] + s_red[1] + s_red[2] + s_red[3];
}

__device__ void ln_inplace(float* row, const float* gam, const float* bet, float* s_red) {
  float ps = 0.f;
  for (int d = threadIdx.x; d < D; d += NT) ps += row[d];
  const float m = bred_sum(ps, s_red) * (1.0f / 640.0f);
  float pv = 0.f;
  for (int d = threadIdx.x; d < D; d += NT) { float t = row[d] - m; pv += t * t; }
  const float var = bred_sum(pv, s_red) * (1.0f / 640.0f);
  const float rstd = 1.0f / sqrtf(var + 1e-6f);
  for (int d = threadIdx.x; d < D; d += NT)
    row[d] = (row[d] - m) * rstd * gam[d] + bet[d];
  __syncthreads();
}

// wave-local LN over s_x[w][640], wave w = row w. No barriers inside.
__device__ __forceinline__ void ln_wave(float* s_x, const float* gam, const float* bet) {
  const int tid = threadIdx.x, w = tid >> 6, lane = tid & 63;
  float ps = 0.f;
  for (int i = lane; i < D; i += 64) ps += s_x[w * 640 + i];
  #pragma unroll
  for (int o = 32; o > 0; o >>= 1) ps += __shfl_xor(ps, o, 64);
  const float mean = ps * (1.0f / 640.0f);
  float pv = 0.f;
  for (int i = lane; i < D; i += 64) { float d = s_x[w * 640 + i] - mean; pv += d * d; }
  #pragma unroll
  for (int o = 32; o > 0; o >>= 1) pv += __shfl_xor(pv, o, 64);
  const float rstd = 1.0f / sqrtf(pv * (1.0f / 640.0f) + 1e-6f);
  for (int i = lane; i < D; i += 64)
    s_x[w * 640 + i] = (s_x[w * 640 + i] - mean) * rstd * gam[i] + bet[i];
}

// s_x[w][640] = LN2_{lsrc}( h1v + f2v(2 halves) + b2 ). Wave w = batch row w.
// Deterministic (wave-local shuffles) -> bit-identical across all blocks.
__device__ __forceinline__ void build_x2w(const Par& p, int t, int lsrc, float* s_x) {
  const int tid = threadIdx.x, w = tid >> 6, lane = tid & 63;
  const size_t ver = VER(t, lsrc);
  const float* h1 = g_h1v + ver * 2560 + w * 640;
  const float* fa = g_f2v + ver * 5120 + w * 640;
  const float* fb = g_f2v + ver * 5120 + 2560 + w * 640;
  const float* b2 = p.b2 + (size_t)lsrc * D;
  for (int c4 = lane; c4 < 160; c4 += 64) {
    f4 a = *(const f4*)&h1[c4 * 4];
    f4 b = *(const f4*)&fa[c4 * 4];
    f4 c = *(const f4*)&fb[c4 * 4];
    const float* bb = b2 + c4 * 4;
    f4 s = { a.x + b.x + c.x + bb[0], a.y + b.y + c.y + bb[1],
             a.z + b.z + c.z + bb[2], a.w + b.w + c.w + bb[3] };
    *(f4*)&s_x[w * 640 + c4 * 4] = s;
  }
  ln_wave(s_x, p.ln2s + (size_t)lsrc * D, p.ln2b + (size_t)lsrc * D);
}

// =================== LAYER-SCOPED WEIGHT PREFETCH ============================
// Issue EXACTLY the loads the upcoming GEMM will perform (plain cached),
// BEFORE the stage_wait: the weight stream overlaps predecessor stages and
// the GEMM then hits L1/L2. Per-XCD footprints (QKV 1.2MB, AW 0.2MB,
// F1/F2 0.8MB) fit the 4MB L2 across their windows. NO pf for LM
// (9.6MB/XCD, 2.4x L2 -> R12 showed it self-evicts and poisons everything).

__device__ void pf_QKV(const Par& p, int l) {
  const int tid = threadIdx.x;
  const int cg = (blockIdx.x & 7) * 30 + (blockIdx.x >> 3);
  const int m = cg / 80, colm0 = (cg % 80) * 8;
  const int ds = tid >> 3, c = tid & 7;
  const float* Wb = (m == 0 ? p.Wq : m == 1 ? p.Wk : p.Wv)
                    + (size_t)l * D * D + colm0 + c;
  float s = 0.f;
  #pragma unroll
  for (int j = 0; j < 20; ++j) s += Wb[(size_t)(ds + j * 32) * D];
  keep(s);
}

__device__ void pf_AW(const Par& p, int l) {
  const int idx = blockIdx.x - AW_B, h = idx >> 3, c = idx & 7, tid = threadIdx.x;
  if (tid < 240) {
    const int j = tid % 80, sub = tid / 80;
    const int col = c * 80 + j;
    const int d0 = sub * 27, d1 = (sub == 2) ? 80 : d0 + 27;
    const float* Wo = p.Wo + (size_t)l * D * D + col;
    float s = 0.f;
    for (int dd = d0; dd < d1; ++dd) s += Wo[(size_t)(h * 80 + dd) * D];
    keep(s);
  }
}

__device__ void pf_F1(const Par& p, int l) {
  const int tid = threadIdx.x;
  const int raw = blockIdx.x - F1_B;
  const int cg = (raw & 7) * 40 + (raw >> 3);
  const int col0 = cg * 8;
  const int ds = tid >> 3, c = tid & 7;
  const float* Wb = p.W1 + (size_t)l * D * FF + col0 + c;
  float s = 0.f;
  #pragma unroll
  for (int j = 0; j < 20; ++j) s += Wb[(size_t)(ds + j * 32) * FF];
  keep(s);
}

__device__ void pf_F2(const Par& p, int l) {
  const int idx = blockIdx.x - F2_B, tid = threadIdx.x;
  const int hf = idx / 80, craw = idx % 80;
  const int cg = (craw & 7) * 10 + (craw >> 3);
  const int col0 = cg * 8;
  const int ds = tid >> 3, c = tid & 7;
  const float* Wb = p.W2 + (size_t)l * FF * D + (size_t)hf * 1280 * D + col0 + c;
  float s = 0.f;
  #pragma unroll
  for (int kb = 0; kb < 40; ++kb) s += Wb[(size_t)(ds + kb * 32) * D];
  keep(s);
}

// =================== DECODE STAGES ===========================================

// QKV (fused LN2 of previous layer): blocks [0,240): 8 cols of 1920,
// full depth 640. XCD-grouped slice swizzle (240 = 8*30).
__device__ void st_QKV(const Par& p, int l, int t, float* s_x, float* s_t, float* s_r) {
  const int tid = threadIdx.x;
  const int cg = (blockIdx.x & 7) * 30 + (blockIdx.x >> 3);   // bijective
  const int m = cg / 80, colm0 = (cg % 80) * 8;
  const int w = tid >> 6, lane = tid & 63;
  if (l == 0) {
    const int tok = g_tokv[t * 64 + w];          // versioned, plain
    for (int c4 = lane; c4 < 160; c4 += 64)
      *(f4*)&s_x[w * 640 + c4 * 4] = *(const f4*)&p.emb[(size_t)tok * D + c4 * 4];
  } else {
    build_x2w(p, t, l - 1, s_x);
  }
  __syncthreads();
  if (cg == 0) {  // publish x for F1's residual (blockIdx 0 -> cg 0)
    const size_t xo = VER(t, l) * 2560;
    for (int i = tid; i < 640; i += NT)
      st4c(&g_xv[xo + (size_t)i * 4], *(f4*)&s_x[i * 4]);
  }
  // ---- GEMM: 8 cols, full depth 640; thread = (ds in [0,32), c in [0,8)).
  const int ds = tid >> 3, c = tid & 7;
  const float* Wb = (m == 0 ? p.Wq : m == 1 ? p.Wk : p.Wv)
                    + (size_t)l * D * D + colm0 + c;
  float a0 = 0, a1 = 0, a2 = 0, a3 = 0;
  {
    float wv[20];
    #pragma unroll
    for (int j = 0; j < 20; ++j) wv[j] = Wb[(size_t)(ds + j * 32) * D];
    #pragma unroll
    for (int j = 0; j < 20; ++j) {
      const int dd = ds + j * 32;
      a0 = fmaf(s_x[dd],        wv[j], a0);
      a1 = fmaf(s_x[640 + dd],  wv[j], a1);
      a2 = fmaf(s_x[1280 + dd], wv[j], a2);
      a3 = fmaf(s_x[1920 + dd], wv[j], a3);
    }
  }
  { f4 av = { a0, a1, a2, a3 }; *(f4*)&s_t[c * 132 + ds * 4] = av; }
  __syncthreads();
  if (tid < 32) {
    const int c2 = tid >> 2, b = tid & 3;
    float v = 0.f;
    #pragma unroll
    for (int d2 = 0; d2 < 32; ++d2) v += s_t[c2 * 132 + d2 * 4 + b];
    v += (m == 0 ? p.bq : m == 1 ? p.bk : p.bv)[(size_t)l * D + colm0 + c2];
    s_r[c2 * 4 + b] = v;
  }
  __syncthreads();
  if (m == 0) {
    if (tid < 8) {
      f4 v = { s_r[tid * 4], s_r[tid * 4 + 1], s_r[tid * 4 + 2], s_r[tid * 4 + 3] };
      st4c(&g_qv[VER(t, l) * 2560 + (size_t)(colm0 + tid) * 4], v);
    }
  } else {
    const int h = colm0 / 80, j0 = colm0 % 80;
    if (tid < 8) {
      const int b = tid >> 1, cq4 = (tid & 1) * 4;
      f4 v = { s_r[(cq4+0)*4+b], s_r[(cq4+1)*4+b], s_r[(cq4+2)*4+b], s_r[(cq4+3)*4+b] };
      float* cache = (m == 1) ? g_Kc : g_Vc;
      st4c(&cache[KCIDX(l, b, h, t, j0 + cq4)], v);
    }
  }
}

// AW: blocks [240,304): h=(idx)>>3, c=idx&7. q + all KV rows plain cached.
__device__ void st_AW(const Par& p, int l, int t,
                      float* s_q, float* s_sc, float* s_o, float* s_wo) {
  const int idx = blockIdx.x - AW_B, h = idx >> 3, c = idx & 7, tid = threadIdx.x;
  const size_t qo = VER(t, l) * 2560;
  if (tid < 80) {
    f4 q = *(const f4*)&g_qv[qo + (size_t)(h * 80 + tid) * 4];
    s_q[tid] = q.x; s_q[80 + tid] = q.y; s_q[160 + tid] = q.z; s_q[240 + tid] = q.w;
  }
  __syncthreads();
  const int nk = t + 1;
  for (int task = tid; task < 4 * nk; task += NT) {
    const int b = task / nk, kp = task % nk;
    const float* qq = s_q + b * 80;
    const f4* kk = (const f4*)&g_Kc[KCIDX(l, b, h, kp, 0)];
    float sd = 0.f;
    #pragma unroll
    for (int j4 = 0; j4 < 20; ++j4) {
      f4 k4 = kk[j4];
      sd += qq[j4*4+0]*k4.x + qq[j4*4+1]*k4.y + qq[j4*4+2]*k4.z + qq[j4*4+3]*k4.w;
    }
    s_sc[b * 33 + kp] = sd / 8.94427190999915878564f;
  }
  __syncthreads();
  if (tid < 4) {
    const int b = tid;
    float m = -1e30f;
    for (int k = 0; k < nk; ++k) m = fmaxf(m, s_sc[b * 33 + k]);
    float sum = 0.f;
    for (int k = 0; k < nk; ++k) { float e = expf(s_sc[b * 33 + k] - m); s_sc[b * 33 + k] = e; sum += e; }
    s_sc[132 + b] = 1.0f / sum;
  }
  __syncthreads();
  if (tid < 80) {
    const int b = tid / 20, j4 = tid % 20;
    f4 acc = { 0.f, 0.f, 0.f, 0.f };
    for (int kp = 0; kp < nk; ++kp) {
      f4 v = *(const f4*)&g_Vc[KCIDX(l, b, h, kp, j4 * 4)];
      const float wgt = s_sc[b * 33 + kp];
      acc.x += wgt * v.x; acc.y += wgt * v.y; acc.z += wgt * v.z; acc.w += wgt * v.w;
    }
    const float r = s_sc[132 + b];
    f4 o = { acc.x * r, acc.y * r, acc.z * r, acc.w * r };
    *(f4*)&s_o[b * 80 + j4 * 4] = o;
  }
  __syncthreads();
  // Wo partial: cols [c*80,+80), rows h*80+[0,80) split in 3 subs
  if (tid < 240) {
    const int j = tid % 80, sub = tid / 80;
    const int col = c * 80 + j;
    const int d0 = sub * 27, d1 = (sub == 2) ? 80 : d0 + 27;
    const float* Wo = p.Wo + (size_t)l * D * D + col;
    float a0 = 0, a1 = 0, a2 = 0, a3 = 0;
    #pragma unroll 9
    for (int dd = d0; dd < d1; ++dd) {
      const float w = Wo[(size_t)(h * 80 + dd) * D];
      a0 += s_o[0*80+dd] * w; a1 += s_o[80+dd] * w;
      a2 += s_o[160+dd] * w; a3 += s_o[240+dd] * w;
    }
    float* tp = s_wo + (j * 3 + sub) * 4;
    tp[0] = a0; tp[1] = a1; tp[2] = a2; tp[3] = a3;
  }
  __syncthreads();
  if (tid < 80) {
    const int b = tid / 20, cq = tid % 20;
    f4 v;
    #pragma unroll
    for (int i = 0; i < 4; ++i) {
      const int j = cq * 4 + i;
      v[i] = s_wo[(j*3+0)*4+b] + s_wo[(j*3+1)*4+b] + s_wo[(j*3+2)*4+b];
    }
    st4c(&g_opartv[VER(t, l) * 20480 + (size_t)(h * 4 + b) * 640 + c * 80 + cq * 4], v);
  }
}

// F1 (fused residual + LN1): blocks [304,624): 8 cols of FF, full depth.
// Each block builds h1 = LN1(xv + bo + sum_h opartv) wave-locally, then GEMM.
// raw==0 publishes h1v. XCD-grouped swizzle (320 = 8*40).
__device__ void st_F1(const Par& p, int l, int t, float* s_x, float* s_t, float* s_r) {
  const int tid = threadIdx.x;
  const int raw = blockIdx.x - F1_B;
  const int cg = (raw & 7) * 40 + (raw >> 3);
  const int col0 = cg * 8;
  const size_t ver = VER(t, l);
  const int w = tid >> 6, lane = tid & 63;
  // ---- residual + LN1, wave w = batch row w
  {
    const float* xv = g_xv + ver * 2560 + w * 640;
    const float* bo = p.bo + (size_t)l * D;
    for (int c4 = lane; c4 < 160; c4 += 64) {
      f4 a = *(const f4*)&xv[c4 * 4];
      const float* bb = bo + c4 * 4;
      a.x += bb[0]; a.y += bb[1]; a.z += bb[2]; a.w += bb[3];
      #pragma unroll
      for (int h = 0; h < 8; ++h) {
        f4 ov = *(const f4*)&g_opartv[ver * 20480 + (size_t)(h * 4 + w) * 640 + c4 * 4];
        a.x += ov.x; a.y += ov.y; a.z += ov.z; a.w += ov.w;
      }
      *(f4*)&s_x[w * 640 + c4 * 4] = a;
    }
    ln_wave(s_x, p.ln1s + (size_t)l * D, p.ln1b + (size_t)l * D);
  }
  __syncthreads();
  if (raw == 0) {  // publish h1 for next-layer QKV / LM
    for (int i = tid; i < 640; i += NT)
      st4c(&g_h1v[ver * 2560 + (size_t)i * 4], *(f4*)&s_x[i * 4]);
  }
  // ---- GEMM: 8 cols, depth 640; thread = (ds in [0,32), c in [0,8)).
  const int ds = tid >> 3, c = tid & 7;
  const float* Wb = p.W1 + (size_t)l * D * FF + col0 + c;
  float a0 = 0, a1 = 0, a2 = 0, a3 = 0;
  {
    float wv[20];
    #pragma unroll
    for (int j = 0; j < 20; ++j) wv[j] = Wb[(size_t)(ds + j * 32) * FF];
    #pragma unroll
    for (int j = 0; j < 20; ++j) {
      const int dd = ds + j * 32;
      a0 = fmaf(s_x[dd],        wv[j], a0);
      a1 = fmaf(s_x[640 + dd],  wv[j], a1);
      a2 = fmaf(s_x[1280 + dd], wv[j], a2);
      a3 = fmaf(s_x[1920 + dd], wv[j], a3);
    }
  }
  { f4 av = { a0, a1, a2, a3 }; *(f4*)&s_t[c * 132 + ds * 4] = av; }
  __syncthreads();
  if (tid < 32) {
    const int c2 = tid >> 2, b = tid & 3;
    float v = 0.f;
    #pragma unroll
    for (int d2 = 0; d2 < 32; ++d2) v += s_t[c2 * 132 + d2 * 4 + b];
    v += p.b1[(size_t)l * FF + col0 + c2];
    s_r[c2 * 4 + b] = fmaxf(v, 0.f);
  }
  __syncthreads();
  if (tid < 8) {
    const int b = tid >> 1, cq4 = (tid & 1) * 4;
    f4 v = { s_r[(cq4+0)*4+b], s_r[(cq4+1)*4+b], s_r[(cq4+2)*4+b], s_r[(cq4+3)*4+b] };
    st4c(&g_f1v[ver * 10240 + (size_t)b * 2560 + col0 + cq4], v);
  }
}

// F2: blocks [624,784): hf=idx/80 (depth half), 8 cols, depth 1280.
// XCD-grouped swizzle within each hf (80 = 8*10).
__device__ void st_F2(const Par& p, int l, int t, float* s_f, float* s_t, float* s_r) {
  const int idx = blockIdx.x - F2_B, tid = threadIdx.x;
  const int hf = idx / 80, craw = idx % 80;
  const int cg = (craw & 7) * 10 + (craw >> 3);
  const int col0 = cg * 8;
  const size_t ver = VER(t, l);
  #pragma unroll
  for (int i = 0; i < 5; ++i) {
    const int ii = tid + i * NT;              // 0..1279
    const int b = ii / 320, fo = ii % 320;
    *(f4*)&s_f[b * 1280 + fo * 4] =
        *(const f4*)&g_f1v[ver * 10240 + (size_t)b * 2560 + hf * 1280 + fo * 4];
  }
  __syncthreads();
  // ---- GEMM: 8 cols, depth 1280; thread = (ds in [0,32), c in [0,8)), 2x20.
  const int ds = tid >> 3, c = tid & 7;
  const float* Wb = p.W2 + (size_t)l * FF * D + (size_t)hf * 1280 * D + col0 + c;
  float a0 = 0, a1 = 0, a2 = 0, a3 = 0;
  #pragma unroll
  for (int kb = 0; kb < 40; kb += 20) {
    float wv[20];
    #pragma unroll
    for (int j = 0; j < 20; ++j) wv[j] = Wb[(size_t)(ds + (kb + j) * 32) * D];
    #pragma unroll
    for (int j = 0; j < 20; ++j) {
      const int dl = ds + (kb + j) * 32;
      a0 = fmaf(s_f[dl],        wv[j], a0);
      a1 = fmaf(s_f[1280 + dl], wv[j], a1);
      a2 = fmaf(s_f[2560 + dl], wv[j], a2);
      a3 = fmaf(s_f[3840 + dl], wv[j], a3);
    }
  }
  { f4 av = { a0, a1, a2, a3 }; *(f4*)&s_t[c * 132 + ds * 4] = av; }
  __syncthreads();
  if (tid < 32) {
    const int c2 = tid >> 2, b = tid & 3;
    float v = 0.f;
    #pragma unroll
    for (int d2 = 0; d2 < 32; ++d2) v += s_t[c2 * 132 + d2 * 4 + b];
    s_r[c2 * 4 + b] = v;
  }
  __syncthreads();
  if (tid < 8) {
    const int b = tid >> 1, cq4 = (tid & 1) * 4;
    f4 v = { s_r[(cq4+0)*4+b], s_r[(cq4+1)*4+b], s_r[(cq4+2)*4+b], s_r[(cq4+3)*4+b] };
    st4c(&g_f2v[ver * 5120 + (size_t)(hf * 4 + b) * 640 + col0 + cq4], v);
  }
}

// LM: blocks [0,938): 32 cols each, depth split 8x80, 4x20 batched weights.
// src==1 (decode steps): build x = LN2(h1v+f2v) wave-locally (fused RL).
// src==0 (first step): read prefill-produced g_xlm.
// Bijective XCD chunk swizzle (938 = 8*117 + 2).
__device__ void st_LM(const Par& p, int t, int src, float* s_xf, float* s_part,
                      unsigned long long* s_key) {
  const int bid = blockIdx.x, tid = threadIdx.x;
  const int xcd = bid & 7, jj = bid >> 3;
  const int chunk = (xcd < 2 ? xcd * 118 : 236 + (xcd - 2) * 117) + jj;
  if (src == 0) {
    #pragma unroll
    for (int i = 0; i < 3; ++i) {
      const int idx = tid + i * NT;
      if (idx < 640) *(f4*)&s_xf[idx * 4] = *(const f4*)&g_xlm[(size_t)t * 2560 + (size_t)idx * 4];
    }
  } else {
    build_x2w(p, t, NL - 1, s_xf);
  }
  __syncthreads();
  const int sg = tid >> 5, cj = tid & 31;
  const int col = chunk * 32 + cj;
  float a0 = 0, a1 = 0, a2 = 0, a3 = 0;
  if (col < V) {
    const float* W = p.lmW + (size_t)sg * 80 * V + col;
    #pragma unroll
    for (int kb = 0; kb < 80; kb += 20) {
      float w[20];
      #pragma unroll
      for (int j = 0; j < 20; ++j) w[j] = W[(size_t)(kb + j) * V];
      #pragma unroll
      for (int j = 0; j < 20; ++j) {
        const int d = sg * 80 + kb + j;
        a0 = fmaf(s_xf[d],        w[j], a0);
        a1 = fmaf(s_xf[640 + d],  w[j], a1);
        a2 = fmaf(s_xf[1280 + d], w[j], a2);
        a3 = fmaf(s_xf[1920 + d], w[j], a3);
      }
    }
  }
  float* tp = s_part + (sg * 32 + cj) * 4;
  tp[0] = a0; tp[1] = a1; tp[2] = a2; tp[3] = a3;
  __syncthreads();
  if (tid < 128) {
    const int cj2 = tid >> 2, b = tid & 3, col2 = chunk * 32 + cj2;
    unsigned long long key = 0ull;
    if (col2 < V) {
      float a = p.lmb[col2];
      #pragma unroll
      for (int sg2 = 0; sg2 < 8; ++sg2) a += s_part[(sg2 * 32 + cj2) * 4 + b];
      unsigned u = __float_as_uint(a);
      u = (u & 0x80000000u) ? ~u : (u | 0x80000000u);
      key = ((unsigned long long)u << 32) | (unsigned)(V - col2);
    }
    s_key[cj2 * 4 + b] = key;
  }
  __syncthreads();
  if (tid < 4) {
    unsigned long long k0 = 0ull;
    for (int cj2 = 0; cj2 < 32; ++cj2) {
      const unsigned long long k = s_key[cj2 * 4 + tid];
      if (k > k0) k0 = k;
    }
    stcu64(&g_keys[(size_t)bid * B + tid], k0);
  }
}

// CTL: block 1023. Batched 16B sc1 loads, all 4 batch rows in one pass.
// Final verdict is signaled via g_stopv[t*64] = 1 | stop<<1 (always nonzero),
// AFTER a vmcnt drain so token stores are visible first. No separate flag hop.
__device__ void st_CTL(int t, unsigned long long* s_k64, int* s_ctl) {
  const int tid = threadIdx.x;
  const int i0 = tid, i1 = tid + NT, i2 = tid + 2 * NT, i3 = tid + 3 * NT;
  f4 z = { 0.f, 0.f, 0.f, 0.f };
  f4 ka0, kb0, ka1, kb1, ka2, kb2, ka3 = z, kb3 = z;
  ld4c_issue(ka0, (const float*)&g_keys[(size_t)i0 * 4]);
  ld4c_issue(kb0, (const float*)&g_keys[(size_t)i0 * 4 + 2]);
  ld4c_issue(ka1, (const float*)&g_keys[(size_t)i1 * 4]);
  ld4c_issue(kb1, (const float*)&g_keys[(size_t)i1 * 4 + 2]);
  ld4c_issue(ka2, (const float*)&g_keys[(size_t)i2 * 4]);
  ld4c_issue(kb2, (const float*)&g_keys[(size_t)i2 * 4 + 2]);
  if (i3 < LM_NB) {
    ld4c_issue(ka3, (const float*)&g_keys[(size_t)i3 * 4]);
    ld4c_issue(kb3, (const float*)&g_keys[(size_t)i3 * 4 + 2]);
  }
  wait_vm();
  unsigned long long m0 = mk64(ka0.x, ka0.y), m1 = mk64(ka0.z, ka0.w);
  unsigned long long m2 = mk64(kb0.x, kb0.y), m3 = mk64(kb0.z, kb0.w);
  { unsigned long long s;
    s = mk64(ka1.x,ka1.y); if (s>m0) m0=s;  s = mk64(ka1.z,ka1.w); if (s>m1) m1=s;
    s = mk64(kb1.x,kb1.y); if (s>m2) m2=s;  s = mk64(kb1.z,kb1.w); if (s>m3) m3=s;
    s = mk64(ka2.x,ka2.y); if (s>m0) m0=s;  s = mk64(ka2.z,ka2.w); if (s>m1) m1=s;
    s = mk64(kb2.x,kb2.y); if (s>m2) m2=s;  s = mk64(kb2.z,kb2.w); if (s>m3) m3=s;
    s = mk64(ka3.x,ka3.y); if (s>m0) m0=s;  s = mk64(ka3.z,ka3.w); if (s>m1) m1=s;
    s = mk64(kb3.x,kb3.y); if (s>m2) m2=s;  s = mk64(kb3.z,kb3.w); if (s>m3) m3=s;
  }
  #pragma unroll
  for (int o = 32; o > 0; o >>= 1) {
    unsigned long long s;
    s = __shfl_down(m0, o, 64); if (s > m0) m0 = s;
    s = __shfl_down(m1, o, 64); if (s > m1) m1 = s;
    s = __shfl_down(m2, o, 64); if (s > m2) m2 = s;
    s = __shfl_down(m3, o, 64); if (s > m3) m3 = s;
  }
  if ((tid & 63) == 0) {
    const int w = tid >> 6;
    s_k64[w * 4 + 0] = m0; s_k64[w * 4 + 1] = m1;
    s_k64[w * 4 + 2] = m2; s_k64[w * 4 + 3] = m3;
  }
  __syncthreads();
  if (tid == 0) {
    #pragma unroll
    for (int b = 0; b < B; ++b) {
      unsigned long long k0 = s_k64[b];
      #pragma unroll
      for (int w = 1; w < 4; ++w) if (s_k64[w * 4 + b] > k0) k0 = s_k64[w * 4 + b];
      const int tok = V - (int)(unsigned)(k0 & 0xFFFFFFFFull);
      stci(&g_tokens[b * SEQ + t + 1], tok);
      stci(&g_tokv[(t + 1) * 64 + b], tok);
      s_ctl[b] = tok;
    }
    int stop = (t == MAXLEN - 1) ? 1 : 0;
    if (s_ctl[0] == EOS_TOK && s_ctl[1] == EOS_TOK &&
        s_ctl[2] == EOS_TOK && s_ctl[3] == EOS_TOK) stop = 1;
    // drain token stores, then publish the verdict (nonzero = ready)
    asm volatile("s_waitcnt vmcnt(0)" ::: "memory");
    stci(&g_stopv[t * 64], 1 | (stop << 1));
  }
}

// =================== PREFILL STAGES (36 rows, sc1 scalar; runs once) =========

__device__ void st_Qp(const Par& p, int l, float* s_a) {
  const int idx = blockIdx.x, tid = threadIdx.x;
  const int h = idx / 24, rem = idx % 24, s = rem / 3, rg = rem % 3;
  const int r0 = rg * 12, d0 = s * 80;
  for (int i = tid; i < 960; i += NT) {
    const int ri = i / 80, dd = i % 80;
    s_a[i] = ldc(&g_xp[(r0 + ri) * D + d0 + dd]);
  }
  __syncthreads();
  if (tid < 240) {
    const int m = tid / 80, j = tid % 80, col = h * 80 + j;
    const float* W = (m == 0 ? p.Wq : m == 1 ? p.Wk : p.Wv) + (size_t)l * D * D + col;
    float acc[12];
    #pragma unroll
    for (int ri = 0; ri < 12; ++ri) acc[ri] = 0.f;
    for (int dd = 0; dd < 80; ++dd) {
      const float w = W[(size_t)(d0 + dd) * D];
      #pragma unroll
      for (int ri = 0; ri < 12; ++ri) acc[ri] += s_a[ri * 80 + dd] * w;
    }
    float* o = g_qkvpP + ((size_t)s * 1920 + m * 640 + col) * NR_P + r0;
    #pragma unroll
    for (int ri = 0; ri < 12; ++ri) stc(o + ri, acc[ri]);
  }
}

__device__ void st_AWp1(const Par& p, int l) {
  const int idx = blockIdx.x - 192, h = idx >> 2, c = idx & 3, tid = threadIdx.x;
  for (int pp = c; pp < NPOS_P; pp += 4) {
    for (int task = tid; task < 960; task += NT) {
      const int m = task / 320, rem = task % 320, j = rem >> 2, b = rem & 3;
      const int r = pp * 4 + b;
      const int col = m * 640 + h * 80 + j;
      const float* q = g_qkvpP + (size_t)col * NR_P + r;
      float a = 0.f;
      #pragma unroll
      for (int s = 0; s < 8; ++s) a += ldc(q + (size_t)s * 1920 * NR_P);
      a += (m == 0 ? p.bq : m == 1 ? p.bk : p.bv)[(size_t)l * D + h * 80 + j];
      if (m == 0)      stc(&g_qP[((size_t)h * NR_P + r) * DH + j], a);
      else if (m == 1) stc(&g_Kc[KCIDX(l, b, h, pp, j)], a);
      else             stc(&g_Vc[KCIDX(l, b, h, pp, j)], a);
    }
  }
}

__device__ void st_AWp2(const Par& p, int l, float* s_a, float* s_b, float* s_c) {
  const int idx = blockIdx.x - 224, h = idx >> 2, rg = idx & 3, tid = threadIdx.x;
  const int r0 = rg * 9;
  for (int i = tid; i < 720; i += NT) {
    const int ri = i / 80, j = i % 80;
    s_a[i] = ldc(&g_qP[((size_t)h * NR_P + r0 + ri) * DH + j]);
  }
  __syncthreads();
  for (int task = tid; task < 81; task += NT) {
    const int ri = task / 9, kp = task % 9;
    const int r = r0 + ri, pos = r >> 2, b = r & 3;
    if (kp <= pos) {
      const float* kk = g_Kc + KCIDX(l, b, h, kp, 0);
      const float* qq = s_a + ri * 80;
      float sd = 0.f;
      for (int j = 0; j < 80; ++j) sd += qq[j] * ldc(kk + j);
      s_c[ri * 9 + kp] = sd / 8.94427190999915878564f;
    }
  }
  __syncthreads();
  if (tid < 9) {
    const int ri = tid, r = r0 + ri, pos = r >> 2;
    float m = -1e30f;
    for (int k = 0; k <= pos; ++k) m = fmaxf(m, s_c[ri * 9 + k]);
    float sum = 0.f;
    for (int k = 0; k <= pos; ++k) { float e = expf(s_c[ri * 9 + k] - m); s_c[ri * 9 + k] = e; sum += e; }
    s_c[81 + ri] = 1.0f / sum;
  }
  __syncthreads();
  for (int task = tid; task < 720; task += NT) {
    const int ri = task / 80, j = task % 80;
    const int r = r0 + ri, pos = r >> 2, b = r & 3;
    float acc = 0.f;
    for (int kp = 0; kp <= pos; ++kp)
      acc += s_c[ri * 9 + kp] * ldc(&g_Vc[KCIDX(l, b, h, kp, j)]);
    s_b[ri * 80 + j] = acc * s_c[81 + ri];
  }
  __syncthreads();
  if (tid < 160) {
    for (int pass = 0; pass < 4; ++pass) {
      const int col = pass * 160 + tid;
      const float* Wo = p.Wo + (size_t)l * D * D + col;
      float acc[9];
      #pragma unroll
      for (int ri = 0; ri < 9; ++ri) acc[ri] = 0.f;
      for (int dd = 0; dd < 80; ++dd) {
        const float w = Wo[(size_t)(h * 80 + dd) * D];
        #pragma unroll
        for (int ri = 0; ri < 9; ++ri) acc[ri] += s_b[ri * 80 + dd] * w;
      }
      #pragma unroll
      for (int ri = 0; ri < 9; ++ri)
        stc(&g_opartP[((size_t)h * D + col) * NR_P + r0 + ri], acc[ri]);
    }
  }
}

__device__ void st_RFp(const Par& p, int l, float* s_row, float* s_red) {
  const int r = blockIdx.x, tid = threadIdx.x;
  for (int col = tid; col < D; col += NT) {
    float a = ldc(&g_xp[r * D + col]) + p.bo[(size_t)l * D + col];
    #pragma unroll
    for (int h = 0; h < 8; ++h) a += ldc(&g_opartP[((size_t)h * D + col) * NR_P + r]);
    s_row[col] = a;
  }
  __syncthreads();
  ln_inplace(s_row, p.ln1s + (size_t)l * D, p.ln1b + (size_t)l * D, s_red);
  for (int col = tid; col < D; col += NT) stc(&g_h1p[r * D + col], s_row[col]);
}

__device__ void st_F1p(const Par& p, int l, float* s_a) {
  const int idx = blockIdx.x, tid = threadIdx.x;
  const int s = idx / 30, rem = idx % 30, cg = rem / 3, rg = rem % 3;
  const int r0 = rg * 12, d0 = s * 80;
  for (int i = tid; i < 960; i += NT) {
    const int ri = i / 80, dd = i % 80;
    s_a[i] = ldc(&g_h1p[(r0 + ri) * D + d0 + dd]);
  }
  __syncthreads();
  const int col = cg * 256 + tid;
  const float* W = p.W1 + (size_t)l * D * FF + col;
  float acc[12];
  #pragma unroll
  for (int ri = 0; ri < 12; ++ri) acc[ri] = 0.f;
  for (int dd = 0; dd < 80; ++dd) {
    const float w = W[(size_t)(d0 + dd) * FF];
    #pragma unroll
    for (int ri = 0; ri < 12; ++ri) acc[ri] += s_a[ri * 80 + dd] * w;
  }
  float* o = g_f1pP + ((size_t)s * FF + col) * NR_P + r0;
  #pragma unroll
  for (int ri = 0; ri < 12; ++ri) stc(o + ri, acc[ri]);
}

__device__ void st_F2p(const Par& p, int l, float* s_c) {
  const int idx = blockIdx.x - 240, c = idx / 3, rg = idx % 3, tid = threadIdx.x;
  const int r0 = rg * 12;
  for (int task = tid; task < 960; task += NT) {
    const int ri = task / 80, fj = task % 80;
    const int fcol = c * 80 + fj;
    const float* pp = g_f1pP + (size_t)fcol * NR_P + r0 + ri;
    float a = 0.f;
    #pragma unroll
    for (int s = 0; s < 8; ++s) a += ldc(pp + (size_t)s * FF * NR_P);
    a += p.b1[(size_t)l * FF + fcol];
    s_c[ri * 80 + fj] = fmaxf(a, 0.f);
  }
  __syncthreads();
  for (int pass = 0; pass < 3; ++pass) {
    const int col = pass * 256 + tid;
    if (col < D) {
      const float* W = p.W2 + (size_t)l * FF * D + col;
      float acc[12];
      #pragma unroll
      for (int ri = 0; ri < 12; ++ri) acc[ri] = 0.f;
      for (int fj = 0; fj < 80; ++fj) {
        const float w = W[(size_t)(c * 80 + fj) * D];
        #pragma unroll
        for (int ri = 0; ri < 12; ++ri) acc[ri] += s_c[ri * 80 + fj] * w;
      }
      float* o = g_f2pP + ((size_t)c * D + col) * NR_P + r0;
      #pragma unroll
      for (int ri = 0; ri < 12; ++ri) stc(o + ri, acc[ri]);
    }
  }
}

__device__ void st_RQp(const Par& p, int l, float* s_row, float* s_red) {
  const int r = blockIdx.x, tid = threadIdx.x;
  for (int col = tid; col < D; col += NT) {
    float a = ldc(&g_h1p[r * D + col]) + p.b2[(size_t)l * D + col];
    #pragma unroll 8
    for (int c = 0; c < 32; ++c) a += ldc(&g_f2pP[((size_t)c * D + col) * NR_P + r]);
    s_row[col] = a;
  }
  __syncthreads();
  ln_inplace(s_row, p.ln2s + (size_t)l * D, p.ln2b + (size_t)l * D, s_red);
  for (int col = tid; col < D; col += NT) stc(&g_xp[r * D + col], s_row[col]);
}

__device__ void st_RLp(const Par& p, float* s_row, float* s_red) {
  const int b = blockIdx.x, r = 32 + b, tid = threadIdx.x;
  for (int col = tid; col < D; col += NT) {
    float a = ldc(&g_h1p[r * D + col]) + p.b2[(size_t)(NL - 1) * D + col];
    #pragma unroll 8
    for (int c = 0; c < 32; ++c) a += ldc(&g_f2pP[((size_t)c * D + col) * NR_P + r]);
    s_row[col] = a;
  }
  __syncthreads();
  ln_inplace(s_row, p.ln2s + (size_t)(NL - 1) * D, p.ln2b + (size_t)(NL - 1) * D, s_red);
  for (int col = tid; col < D; col += NT)
    stc(&g_xlm[(size_t)INITLEN * 2560 + (size_t)b * 640 + col], s_row[col]);
}

// =================== MAIN ====================================================
__global__ __launch_bounds__(NT, 4) void tfgen(Par p) {
  __shared__ float s_pool[6400];
  __shared__ float s_red[8];
  __shared__ unsigned long long s_key[128];
  __shared__ int s_ctl[8];

  const int bid = blockIdx.x, tid = threadIdx.x;
  int ep = 0;

  // ---- INIT: zero flags + stop words, prefill embeddings, token buffer
  {
    unsigned* f = g_flags + (size_t)bid * NSLOT * SLOT_U;
    for (int i = tid; i < NSLOT * SLOT_U; i += NT) f[i] = 0u;
  }
  if (bid < NR_P) {
    const int pos = bid >> 2, b = bid & 3;
    const int tk = (pos == 0) ? 1 : p.iw[b * INITLEN + pos - 1];
    for (int d = tid; d < D; d += NT) stc(&g_xp[bid * D + d], p.emb[(size_t)tk * D + d]);
  }
  if (bid == NBLK - 1) {
    for (int i = tid; i < B * SEQ; i += NT) {
      const int b = i / SEQ, pos = i % SEQ;
      int tk = 0;
      if (pos == 0) tk = 1;
      else if (pos <= INITLEN) tk = p.iw[b * INITLEN + pos - 1];
      stci(&g_tokens[i], tk);
    }
    for (int i = tid; i < SEQ; i += NT) stci(&g_stopv[i * 64], 0);  // stale-run reset
  }
  gsync_full();

  // ---- PREFILL (pool-mapped shared arrays)
  float* ps_x  = s_pool;          // 2560
  float* ps_a  = s_pool + 2560;   // 1024
  float* ps_b  = s_pool + 3584;   // 768
  float* ps_c  = s_pool + 4352;   // 1024
  int eRQ = -1, eF2last = -1;
  for (int l = 0; l < NL; ++l) {
    const int eQ = ep++;
    if (bid < 192) { if (l > 0) stage_wait(eRQ, 36); st_Qp(p, l, ps_a); stage_done(eQ); }
    const int eA1 = ep++;
    if (bid >= 192 && bid < 224) { stage_wait(eQ, 192); st_AWp1(p, l); stage_done(eA1); }
    const int eA2 = ep++;
    if (bid >= 224 && bid < 256) { stage_wait(eA1, 32); st_AWp2(p, l, ps_a, ps_b, ps_c); stage_done(eA2); }
    const int eRF = ep++;
    if (bid < NR_P) { stage_wait(eA2, 32); st_RFp(p, l, ps_x, s_red); stage_done(eRF); }
    const int eF1 = ep++;
    if (bid < 240) { stage_wait(eRF, 36); st_F1p(p, l, ps_a); stage_done(eF1); }
    const int eF2 = ep++;
    if (bid >= 240 && bid < 336) { stage_wait(eF1, 240); st_F2p(p, l, ps_c); stage_done(eF2); }
    eF2last = eF2;
    if (l < NL - 1) {
      eRQ = ep++;
      if (bid < NR_P) { stage_wait(eF2, 96); st_RQp(p, l, ps_x, s_red); stage_done(eRQ); }
    }
  }

  // ---- DECODE
  for (int t = INITLEN;; ++t) {
    if (t == INITLEN) {
      const int eRLp = ep++;
      if (bid < 4) { stage_wait(eF2last, 96); st_RLp(p, s_pool, s_red); stage_done(eRLp); }
      const int eLM = ep++;
      if (bid < LM_NB) { stage_wait(eRLp, 4); st_LM(p, t, 0, s_pool, s_pool + 2560, s_key); stage_done(eLM); }
      if (bid == NBLK - 1) { stage_wait(eLM, LM_NB); st_CTL(t, s_key, s_ctl); }
    } else {
      int eF2s = -1;
      for (int l = 0; l < NL; ++l) {
        const int eQKV = ep++;
        if (bid < QKV_N) {
          if (l > 0) { pf_QKV(p, l); stage_wait(eF2s, 160); }
          st_QKV(p, l, t, s_pool, s_pool + 2560, s_pool + 3648);
          stage_done(eQKV);
        }
        const int eAW = ep++;
        if (bid >= AW_B && bid < AW_E) {
          pf_AW(p, l);
          stage_wait(eQKV, QKV_N);
          st_AW(p, l, t, s_pool, s_pool + 320, s_pool + 480, s_pool + 800);
          stage_done(eAW);
        }
        const int eF1 = ep++;
        if (bid >= F1_B && bid < F1_E) {
          pf_F1(p, l);
          stage_wait(eAW, 64);
          st_F1(p, l, t, s_pool, s_pool + 2560, s_pool + 3648);
          stage_done(eF1);
        }
        eF2s = ep++;
        if (bid >= F2_B && bid < F2_E) {
          pf_F2(p, l);
          stage_wait(eF1, 320);
          st_F2(p, l, t, s_pool, s_pool + 5120, s_pool + 6208);
          stage_done(eF2s);
        }
      }
      const int eLM = ep++;
      if (bid < LM_NB) { stage_wait(eF2s, 160); st_LM(p, t, 1, s_pool, s_pool + 2560, s_key); stage_done(eLM); }
      if (bid == NBLK - 1) { stage_wait(eLM, LM_NB); st_CTL(t, s_key, s_ctl); }
    }
    // layer-0 QKV weights for the NEXT step prefetch during the verdict wait
    if (bid < QKV_N) pf_QKV(p, 0);
    // all blocks: CTL's verdict word doubles as the flag (nonzero = ready;
    // token stores were vmcnt-drained before it was written).
    if (tid == 0) {
      int v, spins = 0;
      while ((v = ldci(&g_stopv[t * 64])) == 0) {
        if (spins < 8)        { /* pure spin: poll RTT paces us */ }
        else if (spins < 64)  __builtin_amdgcn_s_sleep(1);
        else if (spins < 192) __builtin_amdgcn_s_sleep(8);
        else                  __builtin_amdgcn_s_sleep(32);
        ++spins;
      }
      s_ctl[4] = v;
    }
    __syncthreads();
    asm volatile("" ::: "memory");
    if (s_ctl[4] >> 1) break;
  }

  if (bid == 0) {
    for (int i = tid; i < B * MAXLEN; i += NT) {
      const int b = i >> 5, j = i & 31;
      p.out[i] = ldci(&g_tokens[b * SEQ + j + 1]);
    }
  }
}

extern "C" void kernel_launch(void* const* d_in, const int* in_sizes, int n_in,
                              void* d_out, int out_size, void* d_ws, size_t ws_size,
                              hipStream_t stream)
{
  (void)in_sizes; (void)n_in; (void)out_size; (void)d_ws; (void)ws_size;
  Par p;
  p.iw   = (const int*)  d_in[0];
  p.emb  = (const float*)d_in[2];
  p.Wq   = (const float*)d_in[3];  p.bq   = (const float*)d_in[4];
  p.Wk   = (const float*)d_in[5];  p.bk   = (const float*)d_in[6];
  p.Wv   = (const float*)d_in[7];  p.bv   = (const float*)d_in[8];
  p.Wo   = (const float*)d_in[9];  p.bo   = (const float*)d_in[10];
  p.ln1s = (const float*)d_in[11]; p.ln1b = (const float*)d_in[12];
  p.W1   = (const float*)d_in[13]; p.b1   = (const float*)d_in[14];
  p.W2   = (const float*)d_in[15]; p.b2   = (const float*)d_in[16];
  p.ln2s = (const float*)d_in[17]; p.ln2b = (const float*)d_in[18];
  p.lmW  = (const float*)d_in[19]; p.lmb  = (const float*)d_in[20];
  p.out  = (int*)d_out;

  void* args[] = { (void*)&p };
  hipError_t err = hipLaunchCooperativeKernel((const void*)tfgen, dim3(NBLK), dim3(NT),
                                              args, 0, stream);
  if (err != hipSuccess) {
    // __launch_bounds__(256,4) guarantees 4 blocks/CU co-residency on 256 CUs.
    hipLaunchKernelGGL(tfgen, dim3(NBLK), dim3(NT), 0, stream, p);
  }
}